// Round 15
// baseline (538.800 us; speedup 1.0000x reference)
//
#include <hip/hip_runtime.h>
#include <math.h>

// ---------------------------------------------------------------------------
// AFPNNet: masked features -> {2-layer GAT, 2-layer GCN} -> concat(encoded)
//          -> recon = relu(enc@Wdec+b), disc = (sigmoid(relu(enc@Wd1+b)@Wd2+b))@Wd3+b
// Outputs flat: recon [N*128] | encoded [N*128] | disc [N]
// h layout: interleaved BF16 [N][128] = [h_gat(64) | h_gcn*dinv_src(64)],
//   256 B/row. csr stores BYTE offsets (src*256). Gather payload bf16; all
//   softmax scalars/coefs/accumulation f32.
// LESSON (r4-r7, reconfirmed r14): ANY global weight load in a const-trip
//   k-loop gets serialized or hoisted by the scheduler -> weights MUST be in
//   LDS. No exceptions.
// LESSON (r8/r9): k_fill 16x write amplification = cross-XCD dirty-line
//   replication -> dst-shard by blockIdx&7 (one XCD per csr region).
// LESSON (r9/r12/r14): dense3 extra enc passes / enc-in-LDS / global-Wd1 all
//   REGRESS vs r11 fused 123KB (125us, DS+VALU co-limited @2 waves/SIMD).
// r15: r11 structure + LDS weights packed BF16: Wdec 32KB + Wd1 16KB + Wd2
//   8KB + sd1 16KB = 72KB -> 2 blocks/CU (4 waves/SIMD) AND halved DS bytes;
//   weight stream stays LDS (scheduler-proof). Unpack = +25% VALU, cheap.
// ---------------------------------------------------------------------------

#define INF_F __int_as_float(0x7f800000)
#define NSHARD 8

__device__ __forceinline__ long edge_at(const void* p, int is64, long i) {
    if (is64) return (long)((const long long*)p)[i];
    return (long)((const int*)p)[i];
}

__device__ __forceinline__ unsigned short f2bf(float f) {   // RNE f32->bf16
    unsigned u = __float_as_uint(f);
    return (unsigned short)((u + 0x7FFFu + ((u >> 16) & 1u)) >> 16);
}
__device__ __forceinline__ float bflo(unsigned p) { return __uint_as_float(p << 16); }
__device__ __forceinline__ float bfhi(unsigned p) { return __uint_as_float(p & 0xFFFF0000u); }
__device__ __forceinline__ unsigned pk2bf(float a, float b) {
    return (unsigned)f2bf(a) | ((unsigned)f2bf(b) << 16);
}

__global__ void k_detect(const int* ew, long words, int* flag) {
    long t = (long)blockIdx.x * blockDim.x + threadIdx.x;
    long stride = words / 8192; if (stride < 1) stride = 1;
    long w = 2 * (t * stride) + 1;
    if (t < 4096 && w < words) {
        if (ew[w] != 0) atomicOr(flag, 1);
    }
}

__global__ void k_deg(const void* edges, long E, const int* flag, int* deg) {
    long e = (long)blockIdx.x * blockDim.x + threadIdx.x;
    if (e >= E) return;
    int is64 = (*flag == 0);
    int d = (int)edge_at(edges, is64, E + e);
    atomicAdd(&deg[d], 1);
}

__global__ void k_scanA(const int* deg, int N, int* offs, int* blockSums) {
    __shared__ int s[256];
    int t = threadIdx.x;
    int i = blockIdx.x * 256 + t;
    int v = (i < N) ? deg[i] : 0;
    s[t] = v;
    for (int off = 1; off < 256; off <<= 1) {
        __syncthreads();
        int u = (t >= off) ? s[t - off] : 0;
        __syncthreads();
        s[t] += u;
    }
    __syncthreads();
    if (i < N) offs[i] = s[t] - v;
    if (t == 255) blockSums[blockIdx.x] = s[255];
}

__global__ void k_scanB(const int* blockSums, int nb, int* blockOff) {
    __shared__ int s[1024];
    int t = threadIdx.x;
    int v = (t < nb) ? blockSums[t] : 0;
    s[t] = v;
    for (int off = 1; off < 1024; off <<= 1) {
        __syncthreads();
        int u = (t >= off) ? s[t - off] : 0;
        __syncthreads();
        s[t] += u;
    }
    __syncthreads();
    if (t < nb) blockOff[t] = s[t] - v;
}

__global__ void k_scanC(int* offs, const int* blockOff, const int* deg,
                        float* dinv, int N, long E) {
    int i = blockIdx.x * 256 + threadIdx.x;
    if (i < N) {
        offs[i] += blockOff[i >> 8];
        int dg = deg[i];
        dinv[i] = dg > 0 ? rsqrtf((float)dg) : 0.0f;
    }
    if (i == 0) offs[N] = (int)E;
}

// XCD-sharded CSR fill (see header LESSON r8/r9).
__global__ void k_fill(const void* edges, long E, const int* flag,
                       const int* offs, int* cursor, int* csr_src, int npp) {
    int bid = blockIdx.x;
    int shard = bid & (NSHARD - 1);
    long e = (long)(bid >> 3) * blockDim.x + threadIdx.x;
    if (e >= E) return;
    int is64 = (*flag == 0);
    int d = (int)edge_at(edges, is64, E + e);
    if (d / npp != shard) return;
    int s = (int)edge_at(edges, is64, e);
    int pos = offs[d] + atomicAdd(&cursor[d], 1);
    csr_src[pos] = s << 8;                 // byte offset into [N][128] bf16 rows
}

// Dense layer 1: K=128 -> h[gn][0:64]=x@Wa, h[gn][64:128]=(x@Wg)*dinv[gn]; bf16 out.
__global__ __launch_bounds__(512) void k_dense1(
    const float* __restrict__ x, const int* __restrict__ mask,
    const float* __restrict__ Wa, const float* __restrict__ Wg,
    const float* __restrict__ aSrc, const float* __restrict__ aDst,
    const float* __restrict__ dinv,
    unsigned short* __restrict__ h16,
    float* __restrict__ a_s, float* __restrict__ a_d, int N)
{
    __shared__ float sW[8192 + 16 + 8192];         // Wa | pad | Wg, 64.1 KB
    int t = threadIdx.x;
    for (int i = t; i < 2048; i += 512) {
        ((float4*)sW)[i] = ((const float4*)Wa)[i];
        ((float4*)(sW + 8208))[i] = ((const float4*)Wg)[i];
    }
    __syncthreads();
    int base = blockIdx.x * 64;
    int tx = t & 31, ny = t >> 5;                  // 16 groups x 4 nodes
    bool gat = tx < 16;
    int jc = (tx & 15) * 4;
    const float* Wp = gat ? sW : (sW + 8208);
    int gn0 = base + ny * 4;
    const float4* xp[4]; float mz[4];
#pragma unroll
    for (int n = 0; n < 4; ++n) {
        int gn = gn0 + n;
        int cl = (gn < N) ? gn : 0;
        xp[n] = (const float4*)(x + (long)cl * 128);
        mz[n] = (gn < N && mask[cl] != 1) ? 1.f : 0.f;
    }
    float acc[4][4];
#pragma unroll
    for (int n = 0; n < 4; ++n) { acc[n][0] = acc[n][1] = acc[n][2] = acc[n][3] = 0.f; }
#pragma unroll 2
    for (int k0 = 0; k0 < 128; k0 += 4) {
        float4 w[4];
#pragma unroll
        for (int kk = 0; kk < 4; ++kk) w[kk] = *(const float4*)&Wp[(k0 + kk) * 64 + jc];
        float4 xr[4];
#pragma unroll
        for (int n = 0; n < 4; ++n) xr[n] = xp[n][k0 >> 2];
#pragma unroll
        for (int kk = 0; kk < 4; ++kk) {
#pragma unroll
            for (int n = 0; n < 4; ++n) {
                float xv = (&xr[n].x)[kk];
                acc[n][0] = fmaf(xv, w[kk].x, acc[n][0]);
                acc[n][1] = fmaf(xv, w[kk].y, acc[n][1]);
                acc[n][2] = fmaf(xv, w[kk].z, acc[n][2]);
                acc[n][3] = fmaf(xv, w[kk].w, acc[n][3]);
            }
        }
    }
#pragma unroll
    for (int n = 0; n < 4; ++n) {
        acc[n][0] *= mz[n]; acc[n][1] *= mz[n]; acc[n][2] *= mz[n]; acc[n][3] *= mz[n];
    }
    float4 as4 = make_float4(0.f, 0.f, 0.f, 0.f), ad4 = as4;
    if (gat) { as4 = *(const float4*)&aSrc[jc]; ad4 = *(const float4*)&aDst[jc]; }
#pragma unroll
    for (int n = 0; n < 4; ++n) {
        int gn = gn0 + n;
        float pa = acc[n][0] * as4.x + acc[n][1] * as4.y + acc[n][2] * as4.z + acc[n][3] * as4.w;
        float pd = acc[n][0] * ad4.x + acc[n][1] * ad4.y + acc[n][2] * ad4.z + acc[n][3] * ad4.w;
#pragma unroll
        for (int off = 8; off; off >>= 1) { pa += __shfl_xor(pa, off); pd += __shfl_xor(pd, off); }
        if (gn < N) {
            if (gat) {
                if (tx == 0) { a_s[gn] = pa; a_d[gn] = pd; }
                ushort4 pk;
                pk.x = f2bf(acc[n][0]); pk.y = f2bf(acc[n][1]);
                pk.z = f2bf(acc[n][2]); pk.w = f2bf(acc[n][3]);
                *(ushort4*)&h16[(long)gn * 128 + jc] = pk;
            } else {
                float dv = dinv[gn];
                ushort4 pk;
                pk.x = f2bf(acc[n][0] * dv); pk.y = f2bf(acc[n][1] * dv);
                pk.z = f2bf(acc[n][2] * dv); pk.w = f2bf(acc[n][3] * dv);
                *(ushort4*)&h16[(long)gn * 128 + 64 + jc] = pk;
            }
        }
    }
}

// Dense layer 2: input o interleaved f32 [N][128], K=64 per branch; bf16 out.
__global__ __launch_bounds__(512) void k_dense2(
    const float* __restrict__ o,
    const float* __restrict__ Wa, const float* __restrict__ Wg,
    const float* __restrict__ aSrc, const float* __restrict__ aDst,
    const float* __restrict__ dinv,
    unsigned short* __restrict__ h16,
    float* __restrict__ a_s, float* __restrict__ a_d, int N)
{
    __shared__ float sW[4096 + 16 + 4096];         // Wa | pad | Wg, 32.1 KB
    int t = threadIdx.x;
    for (int i = t; i < 1024; i += 512) {
        ((float4*)sW)[i] = ((const float4*)Wa)[i];
        ((float4*)(sW + 4112))[i] = ((const float4*)Wg)[i];
    }
    __syncthreads();
    int base = blockIdx.x * 64;
    int tx = t & 31, ny = t >> 5;
    bool gat = tx < 16;
    int jc = (tx & 15) * 4;
    const float* Wp = gat ? sW : (sW + 4112);
    int xoff = gat ? 0 : 16;                       // float4 offset into o row
    int gn0 = base + ny * 4;
    const float4* xp[4];
#pragma unroll
    for (int n = 0; n < 4; ++n) {
        int gn = gn0 + n;
        int cl = (gn < N) ? gn : 0;
        xp[n] = (const float4*)(o + (long)cl * 128) + xoff;
    }
    float acc[4][4];
#pragma unroll
    for (int n = 0; n < 4; ++n) { acc[n][0] = acc[n][1] = acc[n][2] = acc[n][3] = 0.f; }
#pragma unroll 2
    for (int k0 = 0; k0 < 64; k0 += 4) {
        float4 w[4];
#pragma unroll
        for (int kk = 0; kk < 4; ++kk) w[kk] = *(const float4*)&Wp[(k0 + kk) * 64 + jc];
        float4 xr[4];
#pragma unroll
        for (int n = 0; n < 4; ++n) xr[n] = xp[n][k0 >> 2];
#pragma unroll
        for (int kk = 0; kk < 4; ++kk) {
#pragma unroll
            for (int n = 0; n < 4; ++n) {
                float xv = (&xr[n].x)[kk];
                acc[n][0] = fmaf(xv, w[kk].x, acc[n][0]);
                acc[n][1] = fmaf(xv, w[kk].y, acc[n][1]);
                acc[n][2] = fmaf(xv, w[kk].z, acc[n][2]);
                acc[n][3] = fmaf(xv, w[kk].w, acc[n][3]);
            }
        }
    }
    float4 as4 = make_float4(0.f, 0.f, 0.f, 0.f), ad4 = as4;
    if (gat) { as4 = *(const float4*)&aSrc[jc]; ad4 = *(const float4*)&aDst[jc]; }
#pragma unroll
    for (int n = 0; n < 4; ++n) {
        int gn = gn0 + n;
        float pa = acc[n][0] * as4.x + acc[n][1] * as4.y + acc[n][2] * as4.z + acc[n][3] * as4.w;
        float pd = acc[n][0] * ad4.x + acc[n][1] * ad4.y + acc[n][2] * ad4.z + acc[n][3] * ad4.w;
#pragma unroll
        for (int off = 8; off; off >>= 1) { pa += __shfl_xor(pa, off); pd += __shfl_xor(pd, off); }
        if (gn < N) {
            if (gat) {
                if (tx == 0) { a_s[gn] = pa; a_d[gn] = pd; }
                ushort4 pk;
                pk.x = f2bf(acc[n][0]); pk.y = f2bf(acc[n][1]);
                pk.z = f2bf(acc[n][2]); pk.w = f2bf(acc[n][3]);
                *(ushort4*)&h16[(long)gn * 128 + jc] = pk;
            } else {
                float dv = dinv[gn];
                ushort4 pk;
                pk.x = f2bf(acc[n][0] * dv); pk.y = f2bf(acc[n][1] * dv);
                pk.z = f2bf(acc[n][2] * dv); pk.w = f2bf(acc[n][3] * dv);
                *(ushort4*)&h16[(long)gn * 128 + 64 + jc] = pk;
            }
        }
    }
}

// Fused aggregation, wave per dst node. h rows are bf16 (256 B); each lane
// gathers one 4B word = 2 bf16 cols. All math in f32.
template <int MODE>   // 0: layer1 (ELU/ReLU), 1: layer2 (plain)
__global__ __launch_bounds__(512) void k_agg(
    const int* __restrict__ offs, const int* __restrict__ csr,
    const float* __restrict__ a_s, const float* __restrict__ a_d,
    const float* __restrict__ dinv,
    const unsigned short* __restrict__ h16,
    const float* __restrict__ b_a, const float* __restrict__ b_g,
    float* __restrict__ out, int N)
{
    int node = blockIdx.x * 8 + (threadIdx.x >> 6);
    int lane = threadIdx.x & 63;
    if (node >= N) return;
    int p0 = offs[node], p1 = offs[node + 1];
    int deg = p1 - p0;
    float adst = a_d[node];
    float dv = dinv[node];
    bool gat = lane < 32;
    const char* hb = (const char*)h16 + lane * 4;

    float2 res = make_float2(0.f, 0.f);
    if (deg > 0 && deg <= 64) {
        int soff = (lane < deg) ? csr[p0 + lane] : 0;
        float att = -INF_F;
        if (lane < deg) {
            float a = a_s[soff >> 8] + adst;
            att = a >= 0.f ? a : 0.2f * a;
        }
        float m = att;
#pragma unroll
        for (int off = 32; off; off >>= 1) m = fmaxf(m, __shfl_xor(m, off));
        float w = (lane < deg) ? __expf(att - m) : 0.f;
        float den = w;
#pragma unroll
        for (int off = 32; off; off >>= 1) den += __shfl_xor(den, off);
        float coef = w / den;

        float2 a0 = make_float2(0.f, 0.f), a1 = a0, a2 = a0, a3 = a0;
        int e = 0;
        for (; e + 4 <= deg; e += 4) {
            int o0 = __shfl(soff, e),     o1 = __shfl(soff, e + 1);
            int o2 = __shfl(soff, e + 2), o3 = __shfl(soff, e + 3);
            float c0 = __shfl(coef, e),     c1 = __shfl(coef, e + 1);
            float c2 = __shfl(coef, e + 2), c3 = __shfl(coef, e + 3);
            unsigned v0 = *(const unsigned*)(hb + o0);
            unsigned v1 = *(const unsigned*)(hb + o1);
            unsigned v2 = *(const unsigned*)(hb + o2);
            unsigned v3 = *(const unsigned*)(hb + o3);
            float w0 = gat ? c0 : 1.f, w1 = gat ? c1 : 1.f;
            float w2 = gat ? c2 : 1.f, w3 = gat ? c3 : 1.f;
            a0.x = fmaf(bflo(v0), w0, a0.x); a0.y = fmaf(bfhi(v0), w0, a0.y);
            a1.x = fmaf(bflo(v1), w1, a1.x); a1.y = fmaf(bfhi(v1), w1, a1.y);
            a2.x = fmaf(bflo(v2), w2, a2.x); a2.y = fmaf(bfhi(v2), w2, a2.y);
            a3.x = fmaf(bflo(v3), w3, a3.x); a3.y = fmaf(bfhi(v3), w3, a3.y);
        }
        for (; e < deg; ++e) {
            int oe = __shfl(soff, e);
            float ce = __shfl(coef, e);
            unsigned v = *(const unsigned*)(hb + oe);
            float we = gat ? ce : 1.f;
            a0.x = fmaf(bflo(v), we, a0.x); a0.y = fmaf(bfhi(v), we, a0.y);
        }
        res.x = (a0.x + a1.x) + (a2.x + a3.x);
        res.y = (a0.y + a1.y) + (a2.y + a3.y);
    } else if (deg > 64) {
        float m = -INF_F, den = 0.f;
        float2 aa = make_float2(0.f, 0.f);
        for (int p = p0; p < p1; ++p) {
            int soff = csr[p];
            float a = a_s[soff >> 8] + adst;
            float att = a >= 0.f ? a : 0.2f * a;
            float mn = fmaxf(m, att);
            float r = __expf(m - mn);
            float w = __expf(att - mn);
            den = den * r + w;
            unsigned v = *(const unsigned*)(hb + soff);
            float reff = gat ? r : 1.f, weff = gat ? w : 1.f;
            aa.x = fmaf(aa.x, reff, weff * bflo(v));
            aa.y = fmaf(aa.y, reff, weff * bfhi(v));
            m = mn;
        }
        if (gat) { res.x = aa.x / den; res.y = aa.y / den; }
        else     { res = aa; }
    }

    int col = lane * 2;
    float2 ov;
    if (gat) {
        ov.x = res.x + b_a[col];
        ov.y = res.y + b_a[col + 1];
        if (MODE == 0) {
            ov.x = ov.x > 0.f ? ov.x : (__expf(ov.x) - 1.f);
            ov.y = ov.y > 0.f ? ov.y : (__expf(ov.y) - 1.f);
        }
    } else {
        ov.x = dv * res.x + b_g[col - 64];
        ov.y = dv * res.y + b_g[col - 63];
        if (MODE == 0) {
            ov.x = fmaxf(ov.x, 0.f);
            ov.y = fmaxf(ov.y, 0.f);
        }
    }
    *(float2*)&out[(long)node * 128 + col] = ov;
}

// Fused decoder + discriminator. r11 single-pass structure with weights
// packed BF16 in LDS: Wdec 32KB + Wd1 16KB + Wd2 8KB + sd1 16KB = 72.2KB
// -> 2 blocks/CU (4 waves/SIMD) AND halved DS traffic. enc rows from global.
__global__ __launch_bounds__(512) void k_dense3(
    const float* __restrict__ enc,
    const float* __restrict__ Wdec, const float* __restrict__ bdec,
    const float* __restrict__ Wd1, const float* __restrict__ bd1,
    const float* __restrict__ Wd2, const float* __restrict__ bd2,
    const float* __restrict__ Wd3, const float* __restrict__ bd3,
    float* __restrict__ recon, float* __restrict__ disc, int N)
{
    __shared__ unsigned sWdecU[128 * 64];          // 32 KB (bf16 pairs)
    __shared__ unsigned sWd1U[128 * 32];           // 16 KB (bf16 pairs)
    __shared__ float sWd2[64 * 32];                // 8 KB
    __shared__ float sWd3v[32];
    __shared__ float sd1[64 * 64];                 // 16 KB
    int t = threadIdx.x;
    for (int i = t; i < 4096; i += 512) {
        float4 v = ((const float4*)Wdec)[i];
        ((uint2*)sWdecU)[i] = make_uint2(pk2bf(v.x, v.y), pk2bf(v.z, v.w));
    }
    for (int i = t; i < 2048; i += 512) {
        float4 v = ((const float4*)Wd1)[i];
        ((uint2*)sWd1U)[i] = make_uint2(pk2bf(v.x, v.y), pk2bf(v.z, v.w));
    }
    if (t < 512) ((float4*)sWd2)[t] = ((const float4*)Wd2)[t];
    if (t < 32) sWd3v[t] = Wd3[t];
    __syncthreads();
    int base = blockIdx.x * 64;
    int tx = t & 31, ny = t >> 5;                  // 16 groups x 4 nodes
    int jc = tx * 4, jc2 = tx * 2;
    int gn0 = base + ny * 4;
    const float4* ep[4];
#pragma unroll
    for (int n = 0; n < 4; ++n) {
        int gn = gn0 + n;
        int cl = (gn < N) ? gn : 0;
        ep[n] = (const float4*)(enc + (long)cl * 128);
    }

    // Fused A+B: acc = enc@Wdec (4 cols), acc2 = enc@Wd1 (2 cols)
    float acc[4][4], acc2[4][2];
#pragma unroll
    for (int n = 0; n < 4; ++n) {
        acc[n][0] = acc[n][1] = acc[n][2] = acc[n][3] = 0.f;
        acc2[n][0] = acc2[n][1] = 0.f;
    }
#pragma unroll 2
    for (int k0 = 0; k0 < 128; k0 += 4) {
        uint2 wdp[4]; unsigned w1p[4];
#pragma unroll
        for (int kk = 0; kk < 4; ++kk) {
            wdp[kk] = ((const uint2*)sWdecU)[(k0 + kk) * 32 + tx];
            w1p[kk] = sWd1U[(k0 + kk) * 32 + tx];
        }
        float4 xr[4];
#pragma unroll
        for (int n = 0; n < 4; ++n) xr[n] = ep[n][k0 >> 2];
#pragma unroll
        for (int kk = 0; kk < 4; ++kk) {
            float wd0 = bflo(wdp[kk].x), wd1v = bfhi(wdp[kk].x);
            float wd2v = bflo(wdp[kk].y), wd3w = bfhi(wdp[kk].y);
            float w10 = bflo(w1p[kk]),   w11 = bfhi(w1p[kk]);
#pragma unroll
            for (int n = 0; n < 4; ++n) {
                float xv = (&xr[n].x)[kk];
                acc[n][0] = fmaf(xv, wd0, acc[n][0]);
                acc[n][1] = fmaf(xv, wd1v, acc[n][1]);
                acc[n][2] = fmaf(xv, wd2v, acc[n][2]);
                acc[n][3] = fmaf(xv, wd3w, acc[n][3]);
                acc2[n][0] = fmaf(xv, w10, acc2[n][0]);
                acc2[n][1] = fmaf(xv, w11, acc2[n][1]);
            }
        }
    }
    {   // recon epilogue
        float4 bd = *(const float4*)&bdec[jc];
#pragma unroll
        for (int n = 0; n < 4; ++n) {
            int gn = gn0 + n;
            if (gn < N) {
                *(float4*)&recon[(long)gn * 128 + jc] = make_float4(
                    fmaxf(acc[n][0] + bd.x, 0.f), fmaxf(acc[n][1] + bd.y, 0.f),
                    fmaxf(acc[n][2] + bd.z, 0.f), fmaxf(acc[n][3] + bd.w, 0.f));
            }
        }
    }
    {   // d1 -> LDS
        float b1x = bd1[jc2], b1y = bd1[jc2 + 1];
#pragma unroll
        for (int n = 0; n < 4; ++n) {
            float2 v = make_float2(fmaxf(acc2[n][0] + b1x, 0.f), fmaxf(acc2[n][1] + b1y, 0.f));
            *(float2*)&sd1[(ny * 4 + n) * 64 + jc2] = v;
        }
    }
    __syncthreads();

    // Phase C: d2 = d1 @ Wd2 (32 cols, K=64)
    float acc3[4];
#pragma unroll
    for (int n = 0; n < 4; ++n) acc3[n] = 0.f;
    const float* drow = &sd1[ny * 4 * 64];
#pragma unroll 2
    for (int k0 = 0; k0 < 64; k0 += 4) {
        float w1[4];
#pragma unroll
        for (int kk = 0; kk < 4; ++kk) w1[kk] = sWd2[(k0 + kk) * 32 + tx];
        float4 xr[4];
#pragma unroll
        for (int n = 0; n < 4; ++n) xr[n] = *(const float4*)&drow[n * 64 + k0];
#pragma unroll
        for (int kk = 0; kk < 4; ++kk) {
#pragma unroll
            for (int n = 0; n < 4; ++n) acc3[n] = fmaf((&xr[n].x)[kk], w1[kk], acc3[n]);
        }
    }

    // Phase D: disc
    float b2 = bd2[tx];
    float w3 = sWd3v[tx];
    float b3 = bd3[0];
#pragma unroll
    for (int n = 0; n < 4; ++n) {
        int gn = gn0 + n;
        float v = w3 / (1.f + __expf(-(acc3[n] + b2)));
#pragma unroll
        for (int off = 16; off; off >>= 1) v += __shfl_xor(v, off);
        if (tx == 0 && gn < N) disc[gn] = v + b3;
    }
}

extern "C" void kernel_launch(void* const* d_in, const int* in_sizes, int n_in,
                              void* d_out, int out_size, void* d_ws, size_t ws_size,
                              hipStream_t stream)
{
    const float* features = (const float*)d_in[0];
    const void*  edges    = d_in[1];
    const int*   mask     = (const int*)d_in[2];
    const float* W_gat1 = (const float*)d_in[3];
    const float* a_src1 = (const float*)d_in[4];
    const float* a_dst1 = (const float*)d_in[5];
    const float* b_gat1 = (const float*)d_in[6];
    const float* W_gat2 = (const float*)d_in[7];
    const float* a_src2 = (const float*)d_in[8];
    const float* a_dst2 = (const float*)d_in[9];
    const float* b_gat2 = (const float*)d_in[10];
    const float* W_gcn1 = (const float*)d_in[11];
    const float* b_gcn1 = (const float*)d_in[12];
    const float* W_gcn2 = (const float*)d_in[13];
    const float* b_gcn2 = (const float*)d_in[14];
    const float* W_dec  = (const float*)d_in[15];
    const float* b_dec  = (const float*)d_in[16];
    const float* W_d1   = (const float*)d_in[17];
    const float* b_d1   = (const float*)d_in[18];
    const float* W_d2   = (const float*)d_in[19];
    const float* b_d2   = (const float*)d_in[20];
    const float* W_d3   = (const float*)d_in[21];
    const float* b_d3   = (const float*)d_in[22];

    const int  N = in_sizes[0] / 128;
    const long E = (long)in_sizes[1] / 2;

    size_t nP = ((size_t)N + 255) & ~(size_t)255;
    size_t eP = ((size_t)E + 255) & ~(size_t)255;
    int*   deg       = (int*)d_ws;
    int*   offs      = deg + nP;             // uses N+1
    int*   cursor    = offs + nP + 256;
    float* dinv      = (float*)(cursor + nP);
    float* a_s       = dinv + nP;
    float* a_d       = a_s + nP;
    int*   flag      = (int*)(a_d + nP);
    int*   blockSums = flag + 256;
    int*   blockOff  = blockSums + 1024;
    int*   csr       = blockOff + 1024;      // E
    unsigned short* h16 = (unsigned short*)(csr + eP);   // N*128 bf16
    float* o         = (float*)(csr + eP) + nP * 64;     // N*128 f32 (after h16)

    hipMemsetAsync(deg, 0, nP * sizeof(int), stream);
    hipMemsetAsync(cursor, 0, nP * sizeof(int), stream);
    hipMemsetAsync(flag, 0, sizeof(int), stream);

    k_detect<<<16, 256, 0, stream>>>((const int*)edges, 2 * E, flag);

    unsigned eB = (unsigned)((E + 255) / 256);
    k_deg<<<eB, 256, 0, stream>>>(edges, E, flag, deg);

    int nbA = (N + 255) / 256;
    k_scanA<<<nbA, 256, 0, stream>>>(deg, N, offs, blockSums);
    k_scanB<<<1, 1024, 0, stream>>>(blockSums, nbA, blockOff);
    k_scanC<<<nbA, 256, 0, stream>>>(offs, blockOff, deg, dinv, N, E);
    int npp = (N + NSHARD - 1) / NSHARD;
    k_fill<<<eB * NSHARD, 256, 0, stream>>>(edges, E, flag, offs, cursor, csr, npp);

    unsigned dB = (unsigned)((N + 63) / 64);
    unsigned aB = (unsigned)((N + 7) / 8);

    k_dense1<<<dB, 512, 0, stream>>>(features, mask, W_gat1, W_gcn1,
                                     a_src1, a_dst1, dinv,
                                     h16, a_s, a_d, N);
    k_agg<0><<<aB, 512, 0, stream>>>(offs, csr, a_s, a_d, dinv, h16,
                                     b_gat1, b_gcn1, o, N);
    k_dense2<<<dB, 512, 0, stream>>>(o, W_gat2, W_gcn2,
                                     a_src2, a_dst2, dinv,
                                     h16, a_s, a_d, N);
    float* out = (float*)d_out;
    float* enc = out + (long)N * 128;
    k_agg<1><<<aB, 512, 0, stream>>>(offs, csr, a_s, a_d, dinv, h16,
                                     b_gat2, b_gcn2, enc, N);
    k_dense3<<<dB, 512, 0, stream>>>(enc, W_dec, b_dec, W_d1, b_d1,
                                     W_d2, b_d2, W_d3, b_d3,
                                     out, out + (long)N * 256, N);
}

// Round 16
// 472.824 us; speedup vs baseline: 1.1395x; 1.1395x over previous
//
#include <hip/hip_runtime.h>
#include <math.h>

// ---------------------------------------------------------------------------
// AFPNNet: masked features -> {2-layer GAT, 2-layer GCN} -> concat(encoded)
//          -> recon = relu(enc@Wdec+b), disc = (sigmoid(relu(enc@Wd1+b)@Wd2+b))@Wd3+b
// Outputs flat: recon [N*128] | encoded [N*128] | disc [N]
// h layout: interleaved BF16 [N][128]; csr stores BYTE offsets (src*256).
// LESSON (r4-r7, r14): ANY global weight load in a const-trip k-loop gets
//   serialized/hoisted -> weights MUST be staged in LDS. No exceptions.
// LESSON (r8/r9): k_fill write amplification = cross-XCD dirty-line
//   replication -> dst-shard by blockIdx&7.
// LESSON (r8-r15): VALU dense3 plateaus at 125us across 7 variants (DS/VALU/
//   latency trilemma at 157TF vector ceiling).
// r16: dense3 on MATRIX cores (mfma_f32_16x16x32_bf16). k_agg<1> emits bf16
//   enc copy; B-matrices staged as bf16 fragments in LDS (one ds_read_b128
//   per B-frag); one A-frag feeds 12 MFMAs (recon+d1 share A). D layout
//   col=lane&15,row=(lane>>4)*4+reg (HW-verified); A/B: row/col=lane&15,
//   k=(lane>>4)*8+j.
// ---------------------------------------------------------------------------

#define INF_F __int_as_float(0x7f800000)
#define NSHARD 8

typedef __attribute__((ext_vector_type(8))) short bh8;
typedef __attribute__((ext_vector_type(4))) float f32x4;

__device__ __forceinline__ long edge_at(const void* p, int is64, long i) {
    if (is64) return (long)((const long long*)p)[i];
    return (long)((const int*)p)[i];
}

__device__ __forceinline__ unsigned short f2bf(float f) {   // RNE f32->bf16
    unsigned u = __float_as_uint(f);
    return (unsigned short)((u + 0x7FFFu + ((u >> 16) & 1u)) >> 16);
}
__device__ __forceinline__ float bflo(unsigned p) { return __uint_as_float(p << 16); }
__device__ __forceinline__ float bfhi(unsigned p) { return __uint_as_float(p & 0xFFFF0000u); }
__device__ __forceinline__ unsigned pk2bf(float a, float b) {
    return (unsigned)f2bf(a) | ((unsigned)f2bf(b) << 16);
}

__global__ void k_detect(const int* ew, long words, int* flag) {
    long t = (long)blockIdx.x * blockDim.x + threadIdx.x;
    long stride = words / 8192; if (stride < 1) stride = 1;
    long w = 2 * (t * stride) + 1;
    if (t < 4096 && w < words) {
        if (ew[w] != 0) atomicOr(flag, 1);
    }
}

__global__ void k_deg(const void* edges, long E, const int* flag, int* deg) {
    long e = (long)blockIdx.x * blockDim.x + threadIdx.x;
    if (e >= E) return;
    int is64 = (*flag == 0);
    int d = (int)edge_at(edges, is64, E + e);
    atomicAdd(&deg[d], 1);
}

__global__ void k_scanA(const int* deg, int N, int* offs, int* blockSums) {
    __shared__ int s[256];
    int t = threadIdx.x;
    int i = blockIdx.x * 256 + t;
    int v = (i < N) ? deg[i] : 0;
    s[t] = v;
    for (int off = 1; off < 256; off <<= 1) {
        __syncthreads();
        int u = (t >= off) ? s[t - off] : 0;
        __syncthreads();
        s[t] += u;
    }
    __syncthreads();
    if (i < N) offs[i] = s[t] - v;
    if (t == 255) blockSums[blockIdx.x] = s[255];
}

__global__ void k_scanB(const int* blockSums, int nb, int* blockOff) {
    __shared__ int s[1024];
    int t = threadIdx.x;
    int v = (t < nb) ? blockSums[t] : 0;
    s[t] = v;
    for (int off = 1; off < 1024; off <<= 1) {
        __syncthreads();
        int u = (t >= off) ? s[t - off] : 0;
        __syncthreads();
        s[t] += u;
    }
    __syncthreads();
    if (t < nb) blockOff[t] = s[t] - v;
}

__global__ void k_scanC(int* offs, const int* blockOff, const int* deg,
                        float* dinv, int N, long E) {
    int i = blockIdx.x * 256 + threadIdx.x;
    if (i < N) {
        offs[i] += blockOff[i >> 8];
        int dg = deg[i];
        dinv[i] = dg > 0 ? rsqrtf((float)dg) : 0.0f;
    }
    if (i == 0) offs[N] = (int)E;
}

// XCD-sharded CSR fill (see header LESSON r8/r9).
__global__ void k_fill(const void* edges, long E, const int* flag,
                       const int* offs, int* cursor, int* csr_src, int npp) {
    int bid = blockIdx.x;
    int shard = bid & (NSHARD - 1);
    long e = (long)(bid >> 3) * blockDim.x + threadIdx.x;
    if (e >= E) return;
    int is64 = (*flag == 0);
    int d = (int)edge_at(edges, is64, E + e);
    if (d / npp != shard) return;
    int s = (int)edge_at(edges, is64, e);
    int pos = offs[d] + atomicAdd(&cursor[d], 1);
    csr_src[pos] = s << 8;                 // byte offset into [N][128] bf16 rows
}

// Dense layer 1: K=128 -> h[gn][0:64]=x@Wa, h[gn][64:128]=(x@Wg)*dinv[gn]; bf16 out.
__global__ __launch_bounds__(512) void k_dense1(
    const float* __restrict__ x, const int* __restrict__ mask,
    const float* __restrict__ Wa, const float* __restrict__ Wg,
    const float* __restrict__ aSrc, const float* __restrict__ aDst,
    const float* __restrict__ dinv,
    unsigned short* __restrict__ h16,
    float* __restrict__ a_s, float* __restrict__ a_d, int N)
{
    __shared__ float sW[8192 + 16 + 8192];         // Wa | pad | Wg, 64.1 KB
    int t = threadIdx.x;
    for (int i = t; i < 2048; i += 512) {
        ((float4*)sW)[i] = ((const float4*)Wa)[i];
        ((float4*)(sW + 8208))[i] = ((const float4*)Wg)[i];
    }
    __syncthreads();
    int base = blockIdx.x * 64;
    int tx = t & 31, ny = t >> 5;                  // 16 groups x 4 nodes
    bool gat = tx < 16;
    int jc = (tx & 15) * 4;
    const float* Wp = gat ? sW : (sW + 8208);
    int gn0 = base + ny * 4;
    const float4* xp[4]; float mz[4];
#pragma unroll
    for (int n = 0; n < 4; ++n) {
        int gn = gn0 + n;
        int cl = (gn < N) ? gn : 0;
        xp[n] = (const float4*)(x + (long)cl * 128);
        mz[n] = (gn < N && mask[cl] != 1) ? 1.f : 0.f;
    }
    float acc[4][4];
#pragma unroll
    for (int n = 0; n < 4; ++n) { acc[n][0] = acc[n][1] = acc[n][2] = acc[n][3] = 0.f; }
#pragma unroll 2
    for (int k0 = 0; k0 < 128; k0 += 4) {
        float4 w[4];
#pragma unroll
        for (int kk = 0; kk < 4; ++kk) w[kk] = *(const float4*)&Wp[(k0 + kk) * 64 + jc];
        float4 xr[4];
#pragma unroll
        for (int n = 0; n < 4; ++n) xr[n] = xp[n][k0 >> 2];
#pragma unroll
        for (int kk = 0; kk < 4; ++kk) {
#pragma unroll
            for (int n = 0; n < 4; ++n) {
                float xv = (&xr[n].x)[kk];
                acc[n][0] = fmaf(xv, w[kk].x, acc[n][0]);
                acc[n][1] = fmaf(xv, w[kk].y, acc[n][1]);
                acc[n][2] = fmaf(xv, w[kk].z, acc[n][2]);
                acc[n][3] = fmaf(xv, w[kk].w, acc[n][3]);
            }
        }
    }
#pragma unroll
    for (int n = 0; n < 4; ++n) {
        acc[n][0] *= mz[n]; acc[n][1] *= mz[n]; acc[n][2] *= mz[n]; acc[n][3] *= mz[n];
    }
    float4 as4 = make_float4(0.f, 0.f, 0.f, 0.f), ad4 = as4;
    if (gat) { as4 = *(const float4*)&aSrc[jc]; ad4 = *(const float4*)&aDst[jc]; }
#pragma unroll
    for (int n = 0; n < 4; ++n) {
        int gn = gn0 + n;
        float pa = acc[n][0] * as4.x + acc[n][1] * as4.y + acc[n][2] * as4.z + acc[n][3] * as4.w;
        float pd = acc[n][0] * ad4.x + acc[n][1] * ad4.y + acc[n][2] * ad4.z + acc[n][3] * ad4.w;
#pragma unroll
        for (int off = 8; off; off >>= 1) { pa += __shfl_xor(pa, off); pd += __shfl_xor(pd, off); }
        if (gn < N) {
            if (gat) {
                if (tx == 0) { a_s[gn] = pa; a_d[gn] = pd; }
                ushort4 pk;
                pk.x = f2bf(acc[n][0]); pk.y = f2bf(acc[n][1]);
                pk.z = f2bf(acc[n][2]); pk.w = f2bf(acc[n][3]);
                *(ushort4*)&h16[(long)gn * 128 + jc] = pk;
            } else {
                float dv = dinv[gn];
                ushort4 pk;
                pk.x = f2bf(acc[n][0] * dv); pk.y = f2bf(acc[n][1] * dv);
                pk.z = f2bf(acc[n][2] * dv); pk.w = f2bf(acc[n][3] * dv);
                *(ushort4*)&h16[(long)gn * 128 + 64 + jc] = pk;
            }
        }
    }
}

// Dense layer 2: input o interleaved f32 [N][128], K=64 per branch; bf16 out.
__global__ __launch_bounds__(512) void k_dense2(
    const float* __restrict__ o,
    const float* __restrict__ Wa, const float* __restrict__ Wg,
    const float* __restrict__ aSrc, const float* __restrict__ aDst,
    const float* __restrict__ dinv,
    unsigned short* __restrict__ h16,
    float* __restrict__ a_s, float* __restrict__ a_d, int N)
{
    __shared__ float sW[4096 + 16 + 4096];         // Wa | pad | Wg, 32.1 KB
    int t = threadIdx.x;
    for (int i = t; i < 1024; i += 512) {
        ((float4*)sW)[i] = ((const float4*)Wa)[i];
        ((float4*)(sW + 4112))[i] = ((const float4*)Wg)[i];
    }
    __syncthreads();
    int base = blockIdx.x * 64;
    int tx = t & 31, ny = t >> 5;
    bool gat = tx < 16;
    int jc = (tx & 15) * 4;
    const float* Wp = gat ? sW : (sW + 4112);
    int xoff = gat ? 0 : 16;                       // float4 offset into o row
    int gn0 = base + ny * 4;
    const float4* xp[4];
#pragma unroll
    for (int n = 0; n < 4; ++n) {
        int gn = gn0 + n;
        int cl = (gn < N) ? gn : 0;
        xp[n] = (const float4*)(o + (long)cl * 128) + xoff;
    }
    float acc[4][4];
#pragma unroll
    for (int n = 0; n < 4; ++n) { acc[n][0] = acc[n][1] = acc[n][2] = acc[n][3] = 0.f; }
#pragma unroll 2
    for (int k0 = 0; k0 < 64; k0 += 4) {
        float4 w[4];
#pragma unroll
        for (int kk = 0; kk < 4; ++kk) w[kk] = *(const float4*)&Wp[(k0 + kk) * 64 + jc];
        float4 xr[4];
#pragma unroll
        for (int n = 0; n < 4; ++n) xr[n] = xp[n][k0 >> 2];
#pragma unroll
        for (int kk = 0; kk < 4; ++kk) {
#pragma unroll
            for (int n = 0; n < 4; ++n) {
                float xv = (&xr[n].x)[kk];
                acc[n][0] = fmaf(xv, w[kk].x, acc[n][0]);
                acc[n][1] = fmaf(xv, w[kk].y, acc[n][1]);
                acc[n][2] = fmaf(xv, w[kk].z, acc[n][2]);
                acc[n][3] = fmaf(xv, w[kk].w, acc[n][3]);
            }
        }
    }
    float4 as4 = make_float4(0.f, 0.f, 0.f, 0.f), ad4 = as4;
    if (gat) { as4 = *(const float4*)&aSrc[jc]; ad4 = *(const float4*)&aDst[jc]; }
#pragma unroll
    for (int n = 0; n < 4; ++n) {
        int gn = gn0 + n;
        float pa = acc[n][0] * as4.x + acc[n][1] * as4.y + acc[n][2] * as4.z + acc[n][3] * as4.w;
        float pd = acc[n][0] * ad4.x + acc[n][1] * ad4.y + acc[n][2] * ad4.z + acc[n][3] * ad4.w;
#pragma unroll
        for (int off = 8; off; off >>= 1) { pa += __shfl_xor(pa, off); pd += __shfl_xor(pd, off); }
        if (gn < N) {
            if (gat) {
                if (tx == 0) { a_s[gn] = pa; a_d[gn] = pd; }
                ushort4 pk;
                pk.x = f2bf(acc[n][0]); pk.y = f2bf(acc[n][1]);
                pk.z = f2bf(acc[n][2]); pk.w = f2bf(acc[n][3]);
                *(ushort4*)&h16[(long)gn * 128 + jc] = pk;
            } else {
                float dv = dinv[gn];
                ushort4 pk;
                pk.x = f2bf(acc[n][0] * dv); pk.y = f2bf(acc[n][1] * dv);
                pk.z = f2bf(acc[n][2] * dv); pk.w = f2bf(acc[n][3] * dv);
                *(ushort4*)&h16[(long)gn * 128 + 64 + jc] = pk;
            }
        }
    }
}

// Fused aggregation, wave per dst node. h rows bf16; MODE 1 also emits enc16.
template <int MODE>   // 0: layer1 (ELU/ReLU), 1: layer2 (plain)
__global__ __launch_bounds__(512) void k_agg(
    const int* __restrict__ offs, const int* __restrict__ csr,
    const float* __restrict__ a_s, const float* __restrict__ a_d,
    const float* __restrict__ dinv,
    const unsigned short* __restrict__ h16,
    const float* __restrict__ b_a, const float* __restrict__ b_g,
    float* __restrict__ out, unsigned* __restrict__ enc16, int N)
{
    int node = blockIdx.x * 8 + (threadIdx.x >> 6);
    int lane = threadIdx.x & 63;
    if (node >= N) return;
    int p0 = offs[node], p1 = offs[node + 1];
    int deg = p1 - p0;
    float adst = a_d[node];
    float dv = dinv[node];
    bool gat = lane < 32;
    const char* hb = (const char*)h16 + lane * 4;

    float2 res = make_float2(0.f, 0.f);
    if (deg > 0 && deg <= 64) {
        int soff = (lane < deg) ? csr[p0 + lane] : 0;
        float att = -INF_F;
        if (lane < deg) {
            float a = a_s[soff >> 8] + adst;
            att = a >= 0.f ? a : 0.2f * a;
        }
        float m = att;
#pragma unroll
        for (int off = 32; off; off >>= 1) m = fmaxf(m, __shfl_xor(m, off));
        float w = (lane < deg) ? __expf(att - m) : 0.f;
        float den = w;
#pragma unroll
        for (int off = 32; off; off >>= 1) den += __shfl_xor(den, off);
        float coef = w / den;

        float2 a0 = make_float2(0.f, 0.f), a1 = a0, a2 = a0, a3 = a0;
        int e = 0;
        for (; e + 4 <= deg; e += 4) {
            int o0 = __shfl(soff, e),     o1 = __shfl(soff, e + 1);
            int o2 = __shfl(soff, e + 2), o3 = __shfl(soff, e + 3);
            float c0 = __shfl(coef, e),     c1 = __shfl(coef, e + 1);
            float c2 = __shfl(coef, e + 2), c3 = __shfl(coef, e + 3);
            unsigned v0 = *(const unsigned*)(hb + o0);
            unsigned v1 = *(const unsigned*)(hb + o1);
            unsigned v2 = *(const unsigned*)(hb + o2);
            unsigned v3 = *(const unsigned*)(hb + o3);
            float w0 = gat ? c0 : 1.f, w1 = gat ? c1 : 1.f;
            float w2 = gat ? c2 : 1.f, w3 = gat ? c3 : 1.f;
            a0.x = fmaf(bflo(v0), w0, a0.x); a0.y = fmaf(bfhi(v0), w0, a0.y);
            a1.x = fmaf(bflo(v1), w1, a1.x); a1.y = fmaf(bfhi(v1), w1, a1.y);
            a2.x = fmaf(bflo(v2), w2, a2.x); a2.y = fmaf(bfhi(v2), w2, a2.y);
            a3.x = fmaf(bflo(v3), w3, a3.x); a3.y = fmaf(bfhi(v3), w3, a3.y);
        }
        for (; e < deg; ++e) {
            int oe = __shfl(soff, e);
            float ce = __shfl(coef, e);
            unsigned v = *(const unsigned*)(hb + oe);
            float we = gat ? ce : 1.f;
            a0.x = fmaf(bflo(v), we, a0.x); a0.y = fmaf(bfhi(v), we, a0.y);
        }
        res.x = (a0.x + a1.x) + (a2.x + a3.x);
        res.y = (a0.y + a1.y) + (a2.y + a3.y);
    } else if (deg > 64) {
        float m = -INF_F, den = 0.f;
        float2 aa = make_float2(0.f, 0.f);
        for (int p = p0; p < p1; ++p) {
            int soff = csr[p];
            float a = a_s[soff >> 8] + adst;
            float att = a >= 0.f ? a : 0.2f * a;
            float mn = fmaxf(m, att);
            float r = __expf(m - mn);
            float w = __expf(att - mn);
            den = den * r + w;
            unsigned v = *(const unsigned*)(hb + soff);
            float reff = gat ? r : 1.f, weff = gat ? w : 1.f;
            aa.x = fmaf(aa.x, reff, weff * bflo(v));
            aa.y = fmaf(aa.y, reff, weff * bfhi(v));
            m = mn;
        }
        if (gat) { res.x = aa.x / den; res.y = aa.y / den; }
        else     { res = aa; }
    }

    int col = lane * 2;
    float2 ov;
    if (gat) {
        ov.x = res.x + b_a[col];
        ov.y = res.y + b_a[col + 1];
        if (MODE == 0) {
            ov.x = ov.x > 0.f ? ov.x : (__expf(ov.x) - 1.f);
            ov.y = ov.y > 0.f ? ov.y : (__expf(ov.y) - 1.f);
        }
    } else {
        ov.x = dv * res.x + b_g[col - 64];
        ov.y = dv * res.y + b_g[col - 63];
        if (MODE == 0) {
            ov.x = fmaxf(ov.x, 0.f);
            ov.y = fmaxf(ov.y, 0.f);
        }
    }
    *(float2*)&out[(long)node * 128 + col] = ov;
    if (MODE == 1) enc16[(long)node * 64 + lane] = pk2bf(ov.x, ov.y);
}

// Fused decoder + discriminator on MATRIX cores (mfma_f32_16x16x32_bf16).
// 512 thr = 8 waves; block = 128 nodes; wave owns 16 rows.
// B-matrices staged as bf16 fragments in LDS: sB[(nt*KS+ks)*64+lane][8] where
// elem j = W[ks*32+(lane>>4)*8+j][nt*16+(lane&15)]. A-frags: 16B contiguous
// from row-major enc16. D: col=lane&15, row=(lane>>4)*4+reg.
__global__ __launch_bounds__(512) void k_dense3(
    const unsigned short* __restrict__ enc16,
    const float* __restrict__ Wdec, const float* __restrict__ bdec,
    const float* __restrict__ Wd1, const float* __restrict__ bd1,
    const float* __restrict__ Wd2, const float* __restrict__ bd2,
    const float* __restrict__ Wd3, const float* __restrict__ bd3,
    float* __restrict__ recon, float* __restrict__ disc, int N)
{
    __shared__ unsigned short sBdec[8 * 4 * 64 * 8];   // 32 KB
    __shared__ unsigned short sBd1[4 * 4 * 64 * 8];    // 16 KB
    __shared__ unsigned short sBd2[2 * 2 * 64 * 8];    // 4 KB
    __shared__ unsigned short sd1[128 * 64];           // 16 KB (row-major bf16)
    __shared__ float sWd3[32];
    int t = threadIdx.x;
    for (int slot = t; slot < 2048; slot += 512) {     // Wdec: 8nt*4ks*64l
        int l = slot & 63, ntks = slot >> 6, ks = ntks & 3, nt = ntks >> 2;
        int krow = ks * 32 + ((l >> 4) << 3);
        int col = nt * 16 + (l & 15);
#pragma unroll
        for (int j = 0; j < 8; ++j)
            sBdec[slot * 8 + j] = f2bf(Wdec[(krow + j) * 128 + col]);
    }
    for (int slot = t; slot < 1024; slot += 512) {     // Wd1: 4nt*4ks*64l
        int l = slot & 63, ntks = slot >> 6, ks = ntks & 3, nt = ntks >> 2;
        int krow = ks * 32 + ((l >> 4) << 3);
        int col = nt * 16 + (l & 15);
#pragma unroll
        for (int j = 0; j < 8; ++j)
            sBd1[slot * 8 + j] = f2bf(Wd1[(krow + j) * 64 + col]);
    }
    if (t < 256) {                                     // Wd2: 2nt*2ks*64l
        int slot = t;
        int l = slot & 63, ntks = slot >> 6, ks = ntks & 1, nt = ntks >> 1;
        int krow = ks * 32 + ((l >> 4) << 3);
        int col = nt * 16 + (l & 15);
#pragma unroll
        for (int j = 0; j < 8; ++j)
            sBd2[slot * 8 + j] = f2bf(Wd2[(krow + j) * 32 + col]);
    }
    if (t < 32) sWd3[t] = Wd3[t];
    __syncthreads();

    int w = t >> 6, lane = t & 63;
    int base = blockIdx.x * 128 + w * 16;
    int arow = base + (lane & 15);
    int acl = arow < N ? arow : 0;
    const unsigned short* ap = enc16 + (long)acl * 128 + ((lane >> 4) << 3);

    f32x4 accR[8], accD1[4];
#pragma unroll
    for (int i = 0; i < 8; ++i) accR[i] = (f32x4){0.f, 0.f, 0.f, 0.f};
#pragma unroll
    for (int i = 0; i < 4; ++i) accD1[i] = (f32x4){0.f, 0.f, 0.f, 0.f};
#pragma unroll
    for (int ks = 0; ks < 4; ++ks) {
        bh8 a = *(const bh8*)(ap + ks * 32);
#pragma unroll
        for (int nt = 0; nt < 8; ++nt) {
            bh8 b = *(const bh8*)&sBdec[((nt * 4 + ks) * 64 + lane) * 8];
            accR[nt] = __builtin_amdgcn_mfma_f32_16x16x32_bf16(a, b, accR[nt], 0, 0, 0);
        }
#pragma unroll
        for (int nt = 0; nt < 4; ++nt) {
            bh8 b = *(const bh8*)&sBd1[((nt * 4 + ks) * 64 + lane) * 8];
            accD1[nt] = __builtin_amdgcn_mfma_f32_16x16x32_bf16(a, b, accD1[nt], 0, 0, 0);
        }
    }
    // recon epilogue: row = base + (lane>>4)*4 + r, col = nt*16 + (lane&15)
    int rb = base + ((lane >> 4) << 2);
#pragma unroll
    for (int nt = 0; nt < 8; ++nt) {
        int col = nt * 16 + (lane & 15);
        float bcol = bdec[col];
#pragma unroll
        for (int r = 0; r < 4; ++r) {
            int grow = rb + r;
            if (grow < N)
                recon[(long)grow * 128 + col] = fmaxf(accR[nt][r] + bcol, 0.f);
        }
    }
    // d1 -> LDS (bf16 row-major, block-local rows)
    int lrb = w * 16 + ((lane >> 4) << 2);
#pragma unroll
    for (int nt = 0; nt < 4; ++nt) {
        int col = nt * 16 + (lane & 15);
        float bcol = bd1[col];
#pragma unroll
        for (int r = 0; r < 4; ++r)
            sd1[(lrb + r) * 64 + col] = f2bf(fmaxf(accD1[nt][r] + bcol, 0.f));
    }
    __syncthreads();
    // d2 = d1 @ Wd2 (K=64 -> 2 ksteps, N=32 -> 2 ntiles)
    f32x4 accD2[2];
    accD2[0] = (f32x4){0.f, 0.f, 0.f, 0.f};
    accD2[1] = (f32x4){0.f, 0.f, 0.f, 0.f};
#pragma unroll
    for (int ks = 0; ks < 2; ++ks) {
        bh8 a = *(const bh8*)&sd1[(w * 16 + (lane & 15)) * 64 + ks * 32 + ((lane >> 4) << 3)];
#pragma unroll
        for (int nt = 0; nt < 2; ++nt) {
            bh8 b = *(const bh8*)&sBd2[((nt * 2 + ks) * 64 + lane) * 8];
            accD2[nt] = __builtin_amdgcn_mfma_f32_16x16x32_bf16(a, b, accD2[nt], 0, 0, 0);
        }
    }
    // disc: per-row sum over 32 cols of sigmoid(d2+b2)*w3
    float b2a = bd2[lane & 15], b2b = bd2[16 + (lane & 15)];
    float w3a = sWd3[lane & 15], w3b = sWd3[16 + (lane & 15)];
    float b3 = bd3[0];
#pragma unroll
    for (int r = 0; r < 4; ++r) {
        float v = w3a / (1.f + __expf(-(accD2[0][r] + b2a)))
                + w3b / (1.f + __expf(-(accD2[1][r] + b2b)));
        v += __shfl_xor(v, 1); v += __shfl_xor(v, 2);
        v += __shfl_xor(v, 4); v += __shfl_xor(v, 8);
        int grow = rb + r;
        if ((lane & 15) == 0 && grow < N) disc[grow] = v + b3;
    }
}

extern "C" void kernel_launch(void* const* d_in, const int* in_sizes, int n_in,
                              void* d_out, int out_size, void* d_ws, size_t ws_size,
                              hipStream_t stream)
{
    const float* features = (const float*)d_in[0];
    const void*  edges    = d_in[1];
    const int*   mask     = (const int*)d_in[2];
    const float* W_gat1 = (const float*)d_in[3];
    const float* a_src1 = (const float*)d_in[4];
    const float* a_dst1 = (const float*)d_in[5];
    const float* b_gat1 = (const float*)d_in[6];
    const float* W_gat2 = (const float*)d_in[7];
    const float* a_src2 = (const float*)d_in[8];
    const float* a_dst2 = (const float*)d_in[9];
    const float* b_gat2 = (const float*)d_in[10];
    const float* W_gcn1 = (const float*)d_in[11];
    const float* b_gcn1 = (const float*)d_in[12];
    const float* W_gcn2 = (const float*)d_in[13];
    const float* b_gcn2 = (const float*)d_in[14];
    const float* W_dec  = (const float*)d_in[15];
    const float* b_dec  = (const float*)d_in[16];
    const float* W_d1   = (const float*)d_in[17];
    const float* b_d1   = (const float*)d_in[18];
    const float* W_d2   = (const float*)d_in[19];
    const float* b_d2   = (const float*)d_in[20];
    const float* W_d3   = (const float*)d_in[21];
    const float* b_d3   = (const float*)d_in[22];

    const int  N = in_sizes[0] / 128;
    const long E = (long)in_sizes[1] / 2;

    size_t nP = ((size_t)N + 255) & ~(size_t)255;
    size_t eP = ((size_t)E + 255) & ~(size_t)255;
    int*   deg       = (int*)d_ws;
    int*   offs      = deg + nP;             // uses N+1
    int*   cursor    = offs + nP + 256;
    float* dinv      = (float*)(cursor + nP);
    float* a_s       = dinv + nP;
    float* a_d       = a_s + nP;
    int*   flag      = (int*)(a_d + nP);
    int*   blockSums = flag + 256;
    int*   blockOff  = blockSums + 1024;
    int*   csr       = blockOff + 1024;      // E
    unsigned short* h16 = (unsigned short*)(csr + eP);   // N*128 bf16
    float* o         = (float*)(h16 + nP * 128);         // N*128 f32
    unsigned* enc16  = (unsigned*)(o + nP * 128);        // N*64 u32 (bf16 pairs)

    hipMemsetAsync(deg, 0, nP * sizeof(int), stream);
    hipMemsetAsync(cursor, 0, nP * sizeof(int), stream);
    hipMemsetAsync(flag, 0, sizeof(int), stream);

    k_detect<<<16, 256, 0, stream>>>((const int*)edges, 2 * E, flag);

    unsigned eB = (unsigned)((E + 255) / 256);
    k_deg<<<eB, 256, 0, stream>>>(edges, E, flag, deg);

    int nbA = (N + 255) / 256;
    k_scanA<<<nbA, 256, 0, stream>>>(deg, N, offs, blockSums);
    k_scanB<<<1, 1024, 0, stream>>>(blockSums, nbA, blockOff);
    k_scanC<<<nbA, 256, 0, stream>>>(offs, blockOff, deg, dinv, N, E);
    int npp = (N + NSHARD - 1) / NSHARD;
    k_fill<<<eB * NSHARD, 256, 0, stream>>>(edges, E, flag, offs, cursor, csr, npp);

    unsigned dB = (unsigned)((N + 63) / 64);
    unsigned aB = (unsigned)((N + 7) / 8);
    unsigned mB = (unsigned)((N + 127) / 128);

    k_dense1<<<dB, 512, 0, stream>>>(features, mask, W_gat1, W_gcn1,
                                     a_src1, a_dst1, dinv,
                                     h16, a_s, a_d, N);
    k_agg<0><<<aB, 512, 0, stream>>>(offs, csr, a_s, a_d, dinv, h16,
                                     b_gat1, b_gcn1, o, nullptr, N);
    k_dense2<<<dB, 512, 0, stream>>>(o, W_gat2, W_gcn2,
                                     a_src2, a_dst2, dinv,
                                     h16, a_s, a_d, N);
    float* out = (float*)d_out;
    float* enc = out + (long)N * 128;
    k_agg<1><<<aB, 512, 0, stream>>>(offs, csr, a_s, a_d, dinv, h16,
                                     b_gat2, b_gcn2, enc, enc16, N);
    k_dense3<<<mB, 512, 0, stream>>>((const unsigned short*)enc16,
                                     W_dec, b_dec, W_d1, b_d1,
                                     W_d2, b_d2, W_d3, b_d3,
                                     out, out + (long)N * 256, N);
}

// Round 17
// 400.966 us; speedup vs baseline: 1.3438x; 1.1792x over previous
//
#include <hip/hip_runtime.h>
#include <math.h>

// ---------------------------------------------------------------------------
// AFPNNet: masked features -> {2-layer GAT, 2-layer GCN} -> concat(encoded)
//          -> recon = relu(enc@Wdec+b), disc = (sigmoid(relu(enc@Wd1+b)@Wd2+b))@Wd3+b
// Outputs flat: recon [N*128] | encoded [N*128] | disc [N]
// h layout: interleaved BF16 [N][128]; csr stores BYTE offsets (src*256).
// LESSON (r4-r7, r14): ANY global weight load in a const-trip k-loop gets
//   serialized/hoisted -> weights MUST be staged in LDS. No exceptions.
// LESSON (r8/r9): k_fill write amplification = cross-XCD dirty-line
//   replication -> dst-shard by blockIdx&7.
// LESSON (r8-r15): VALU dense kernels plateau (125us dense3 across 7
//   variants); MFMA port (r16) broke the plateau -> ALL dense layers on
//   matrix cores now. D layout col=lane&15,row=(lane>>4)*4+reg (HW-verified);
//   A/B frag: row/col=lane&15, k=(lane>>4)*8+j.
// r17: dense1/dense2 -> unified MFMA kernel k_denseM (B in LDS as bf16
//   frags: dense1 [Wa|Wg], dense2 blockdiag(Wa,Wg)); k_agg<0> emits bf16 o16
//   (dense2 A read direct, no f32 o buffer).
// ---------------------------------------------------------------------------

#define INF_F __int_as_float(0x7f800000)
#define NSHARD 8

typedef __attribute__((ext_vector_type(8))) short bh8;
typedef __attribute__((ext_vector_type(4))) float f32x4;

__device__ __forceinline__ long edge_at(const void* p, int is64, long i) {
    if (is64) return (long)((const long long*)p)[i];
    return (long)((const int*)p)[i];
}

__device__ __forceinline__ unsigned short f2bf(float f) {   // RNE f32->bf16
    unsigned u = __float_as_uint(f);
    return (unsigned short)((u + 0x7FFFu + ((u >> 16) & 1u)) >> 16);
}
__device__ __forceinline__ float bflo(unsigned p) { return __uint_as_float(p << 16); }
__device__ __forceinline__ float bfhi(unsigned p) { return __uint_as_float(p & 0xFFFF0000u); }
__device__ __forceinline__ unsigned pk2bf(float a, float b) {
    return (unsigned)f2bf(a) | ((unsigned)f2bf(b) << 16);
}

__global__ void k_detect(const int* ew, long words, int* flag) {
    long t = (long)blockIdx.x * blockDim.x + threadIdx.x;
    long stride = words / 8192; if (stride < 1) stride = 1;
    long w = 2 * (t * stride) + 1;
    if (t < 4096 && w < words) {
        if (ew[w] != 0) atomicOr(flag, 1);
    }
}

__global__ void k_deg(const void* edges, long E, const int* flag, int* deg) {
    long e = (long)blockIdx.x * blockDim.x + threadIdx.x;
    if (e >= E) return;
    int is64 = (*flag == 0);
    int d = (int)edge_at(edges, is64, E + e);
    atomicAdd(&deg[d], 1);
}

__global__ void k_scanA(const int* deg, int N, int* offs, int* blockSums) {
    __shared__ int s[256];
    int t = threadIdx.x;
    int i = blockIdx.x * 256 + t;
    int v = (i < N) ? deg[i] : 0;
    s[t] = v;
    for (int off = 1; off < 256; off <<= 1) {
        __syncthreads();
        int u = (t >= off) ? s[t - off] : 0;
        __syncthreads();
        s[t] += u;
    }
    __syncthreads();
    if (i < N) offs[i] = s[t] - v;
    if (t == 255) blockSums[blockIdx.x] = s[255];
}

__global__ void k_scanB(const int* blockSums, int nb, int* blockOff) {
    __shared__ int s[1024];
    int t = threadIdx.x;
    int v = (t < nb) ? blockSums[t] : 0;
    s[t] = v;
    for (int off = 1; off < 1024; off <<= 1) {
        __syncthreads();
        int u = (t >= off) ? s[t - off] : 0;
        __syncthreads();
        s[t] += u;
    }
    __syncthreads();
    if (t < nb) blockOff[t] = s[t] - v;
}

__global__ void k_scanC(int* offs, const int* blockOff, const int* deg,
                        float* dinv, int N, long E) {
    int i = blockIdx.x * 256 + threadIdx.x;
    if (i < N) {
        offs[i] += blockOff[i >> 8];
        int dg = deg[i];
        dinv[i] = dg > 0 ? rsqrtf((float)dg) : 0.0f;
    }
    if (i == 0) offs[N] = (int)E;
}

// XCD-sharded CSR fill (see header LESSON r8/r9).
__global__ void k_fill(const void* edges, long E, const int* flag,
                       const int* offs, int* cursor, int* csr_src, int npp) {
    int bid = blockIdx.x;
    int shard = bid & (NSHARD - 1);
    long e = (long)(bid >> 3) * blockDim.x + threadIdx.x;
    if (e >= E) return;
    int is64 = (*flag == 0);
    int d = (int)edge_at(edges, is64, E + e);
    if (d / npp != shard) return;
    int s = (int)edge_at(edges, is64, e);
    int pos = offs[d] + atomicAdd(&cursor[d], 1);
    csr_src[pos] = s << 8;                 // byte offset into [N][128] bf16 rows
}

// Unified MFMA dense layer (mfma_f32_16x16x32_bf16), 128 nodes/block, 8 waves.
// MODE 0 (layer1): A = f32 x [N][128] (mask->0), B = [Wa | Wg] (128x128)
// MODE 1 (layer2): A = bf16 a16 [N][128],        B = blockdiag(Wa, Wg)
// Output: h16[row][0:64] = A@Wa-part, h16[row][64:128] = (A@Wg-part)*dinv[row];
// a_s/a_d = (A@Wa-part) . aSrc/aDst per row.
template <int MODE>
__global__ __launch_bounds__(512) void k_denseM(
    const float* __restrict__ xf, const unsigned short* __restrict__ a16,
    const int* __restrict__ mask,
    const float* __restrict__ Wa, const float* __restrict__ Wg,
    const float* __restrict__ aSrc, const float* __restrict__ aDst,
    const float* __restrict__ dinv,
    unsigned short* __restrict__ h16,
    float* __restrict__ a_s, float* __restrict__ a_d, int N)
{
    __shared__ unsigned short sB[8 * 4 * 64 * 8];      // 32 KB B-fragments
    __shared__ float sAs[64], sAd[64];
    int t = threadIdx.x;
    for (int slot = t; slot < 2048; slot += 512) {     // nt(8) x ks(4) x lane(64)
        int l = slot & 63, ntks = slot >> 6, ks = ntks & 3, nt = ntks >> 2;
        int col = nt * 16 + (l & 15);
        int kbase = ks * 32 + ((l >> 4) << 3);
#pragma unroll
        for (int j = 0; j < 8; ++j) {
            int k = kbase + j;
            float v;
            if (MODE == 0) {
                v = (col < 64) ? Wa[k * 64 + col] : Wg[k * 64 + (col - 64)];
            } else {
                if (col < 64) v = (k < 64) ? Wa[k * 64 + col] : 0.f;
                else          v = (k >= 64) ? Wg[(k - 64) * 64 + (col - 64)] : 0.f;
            }
            sB[slot * 8 + j] = f2bf(v);
        }
    }
    if (t < 64) { sAs[t] = aSrc[t]; sAd[t] = aDst[t]; }
    __syncthreads();

    int w = t >> 6, lane = t & 63;
    int base = blockIdx.x * 128 + w * 16;
    int arow = base + (lane & 15);
    int acl = arow < N ? arow : 0;

    bh8 afr[4];
    if (MODE == 0) {
        float msk = (arow < N && mask[acl] != 1) ? 1.f : 0.f;
        const float* ap = xf + (long)acl * 128 + ((lane >> 4) << 3);
#pragma unroll
        for (int ks = 0; ks < 4; ++ks) {
            float4 u0 = *(const float4*)(ap + ks * 32);
            float4 u1 = *(const float4*)(ap + ks * 32 + 4);
            union { bh8 v; unsigned u4[4]; } cv;
            cv.u4[0] = pk2bf(u0.x * msk, u0.y * msk);
            cv.u4[1] = pk2bf(u0.z * msk, u0.w * msk);
            cv.u4[2] = pk2bf(u1.x * msk, u1.y * msk);
            cv.u4[3] = pk2bf(u1.z * msk, u1.w * msk);
            afr[ks] = cv.v;
        }
    } else {
        const unsigned short* ap = a16 + (long)acl * 128 + ((lane >> 4) << 3);
#pragma unroll
        for (int ks = 0; ks < 4; ++ks) afr[ks] = *(const bh8*)(ap + ks * 32);
    }

    f32x4 acc[8];
#pragma unroll
    for (int i = 0; i < 8; ++i) acc[i] = (f32x4){0.f, 0.f, 0.f, 0.f};
#pragma unroll
    for (int ks = 0; ks < 4; ++ks) {
#pragma unroll
        for (int nt = 0; nt < 8; ++nt) {
            bh8 b = *(const bh8*)&sB[((nt * 4 + ks) * 64 + lane) * 8];
            acc[nt] = __builtin_amdgcn_mfma_f32_16x16x32_bf16(afr[ks], b, acc[nt], 0, 0, 0);
        }
    }

    // epilogue: row = rb + r, col = nt*16 + (lane&15)
    int rb = base + ((lane >> 4) << 2);
    float dvr[4];
#pragma unroll
    for (int r = 0; r < 4; ++r) dvr[r] = (rb + r < N) ? dinv[rb + r] : 0.f;

    // a_s/a_d from Wa-half (nt 0..3)
    float pa[4] = {0.f, 0.f, 0.f, 0.f}, pd[4] = {0.f, 0.f, 0.f, 0.f};
#pragma unroll
    for (int nt = 0; nt < 4; ++nt) {
        float as = sAs[nt * 16 + (lane & 15)];
        float ad = sAd[nt * 16 + (lane & 15)];
#pragma unroll
        for (int r = 0; r < 4; ++r) {
            pa[r] = fmaf(acc[nt][r], as, pa[r]);
            pd[r] = fmaf(acc[nt][r], ad, pd[r]);
        }
    }
#pragma unroll
    for (int r = 0; r < 4; ++r) {
#pragma unroll
        for (int off = 8; off; off >>= 1) {
            pa[r] += __shfl_xor(pa[r], off);
            pd[r] += __shfl_xor(pd[r], off);
        }
        int grow = rb + r;
        if ((lane & 15) == 0 && grow < N) { a_s[grow] = pa[r]; a_d[grow] = pd[r]; }
    }
    // h16 stores
#pragma unroll
    for (int nt = 0; nt < 8; ++nt) {
        int col = nt * 16 + (lane & 15);
        bool gcn = nt >= 4;
#pragma unroll
        for (int r = 0; r < 4; ++r) {
            int grow = rb + r;
            if (grow < N) {
                float v = acc[nt][r];
                if (gcn) v *= dvr[r];
                h16[(long)grow * 128 + col] = f2bf(v);
            }
        }
    }
}

// Fused aggregation, wave per dst node. h rows bf16. MODE 0: writes o16 only.
// MODE 1: writes f32 enc (output) + enc16.
template <int MODE>
__global__ __launch_bounds__(512) void k_agg(
    const int* __restrict__ offs, const int* __restrict__ csr,
    const float* __restrict__ a_s, const float* __restrict__ a_d,
    const float* __restrict__ dinv,
    const unsigned short* __restrict__ h16,
    const float* __restrict__ b_a, const float* __restrict__ b_g,
    float* __restrict__ out, unsigned* __restrict__ o16, int N)
{
    int node = blockIdx.x * 8 + (threadIdx.x >> 6);
    int lane = threadIdx.x & 63;
    if (node >= N) return;
    int p0 = offs[node], p1 = offs[node + 1];
    int deg = p1 - p0;
    float adst = a_d[node];
    float dv = dinv[node];
    bool gat = lane < 32;
    const char* hb = (const char*)h16 + lane * 4;

    float2 res = make_float2(0.f, 0.f);
    if (deg > 0 && deg <= 64) {
        int soff = (lane < deg) ? csr[p0 + lane] : 0;
        float att = -INF_F;
        if (lane < deg) {
            float a = a_s[soff >> 8] + adst;
            att = a >= 0.f ? a : 0.2f * a;
        }
        float m = att;
#pragma unroll
        for (int off = 32; off; off >>= 1) m = fmaxf(m, __shfl_xor(m, off));
        float w = (lane < deg) ? __expf(att - m) : 0.f;
        float den = w;
#pragma unroll
        for (int off = 32; off; off >>= 1) den += __shfl_xor(den, off);
        float coef = w / den;

        float2 a0 = make_float2(0.f, 0.f), a1 = a0, a2 = a0, a3 = a0;
        int e = 0;
        for (; e + 4 <= deg; e += 4) {
            int o0 = __shfl(soff, e),     o1 = __shfl(soff, e + 1);
            int o2 = __shfl(soff, e + 2), o3 = __shfl(soff, e + 3);
            float c0 = __shfl(coef, e),     c1 = __shfl(coef, e + 1);
            float c2 = __shfl(coef, e + 2), c3 = __shfl(coef, e + 3);
            unsigned v0 = *(const unsigned*)(hb + o0);
            unsigned v1 = *(const unsigned*)(hb + o1);
            unsigned v2 = *(const unsigned*)(hb + o2);
            unsigned v3 = *(const unsigned*)(hb + o3);
            float w0 = gat ? c0 : 1.f, w1 = gat ? c1 : 1.f;
            float w2 = gat ? c2 : 1.f, w3 = gat ? c3 : 1.f;
            a0.x = fmaf(bflo(v0), w0, a0.x); a0.y = fmaf(bfhi(v0), w0, a0.y);
            a1.x = fmaf(bflo(v1), w1, a1.x); a1.y = fmaf(bfhi(v1), w1, a1.y);
            a2.x = fmaf(bflo(v2), w2, a2.x); a2.y = fmaf(bfhi(v2), w2, a2.y);
            a3.x = fmaf(bflo(v3), w3, a3.x); a3.y = fmaf(bfhi(v3), w3, a3.y);
        }
        for (; e < deg; ++e) {
            int oe = __shfl(soff, e);
            float ce = __shfl(coef, e);
            unsigned v = *(const unsigned*)(hb + oe);
            float we = gat ? ce : 1.f;
            a0.x = fmaf(bflo(v), we, a0.x); a0.y = fmaf(bfhi(v), we, a0.y);
        }
        res.x = (a0.x + a1.x) + (a2.x + a3.x);
        res.y = (a0.y + a1.y) + (a2.y + a3.y);
    } else if (deg > 64) {
        float m = -INF_F, den = 0.f;
        float2 aa = make_float2(0.f, 0.f);
        for (int p = p0; p < p1; ++p) {
            int soff = csr[p];
            float a = a_s[soff >> 8] + adst;
            float att = a >= 0.f ? a : 0.2f * a;
            float mn = fmaxf(m, att);
            float r = __expf(m - mn);
            float w = __expf(att - mn);
            den = den * r + w;
            unsigned v = *(const unsigned*)(hb + soff);
            float reff = gat ? r : 1.f, weff = gat ? w : 1.f;
            aa.x = fmaf(aa.x, reff, weff * bflo(v));
            aa.y = fmaf(aa.y, reff, weff * bfhi(v));
            m = mn;
        }
        if (gat) { res.x = aa.x / den; res.y = aa.y / den; }
        else     { res = aa; }
    }

    int col = lane * 2;
    float2 ov;
    if (gat) {
        ov.x = res.x + b_a[col];
        ov.y = res.y + b_a[col + 1];
        if (MODE == 0) {
            ov.x = ov.x > 0.f ? ov.x : (__expf(ov.x) - 1.f);
            ov.y = ov.y > 0.f ? ov.y : (__expf(ov.y) - 1.f);
        }
    } else {
        ov.x = dv * res.x + b_g[col - 64];
        ov.y = dv * res.y + b_g[col - 63];
        if (MODE == 0) {
            ov.x = fmaxf(ov.x, 0.f);
            ov.y = fmaxf(ov.y, 0.f);
        }
    }
    if (MODE == 1) *(float2*)&out[(long)node * 128 + col] = ov;
    o16[(long)node * 64 + lane] = pk2bf(ov.x, ov.y);
}

// Fused decoder + discriminator on MATRIX cores (r16, unchanged).
__global__ __launch_bounds__(512) void k_dense3(
    const unsigned short* __restrict__ enc16,
    const float* __restrict__ Wdec, const float* __restrict__ bdec,
    const float* __restrict__ Wd1, const float* __restrict__ bd1,
    const float* __restrict__ Wd2, const float* __restrict__ bd2,
    const float* __restrict__ Wd3, const float* __restrict__ bd3,
    float* __restrict__ recon, float* __restrict__ disc, int N)
{
    __shared__ unsigned short sBdec[8 * 4 * 64 * 8];   // 32 KB
    __shared__ unsigned short sBd1[4 * 4 * 64 * 8];    // 16 KB
    __shared__ unsigned short sBd2[2 * 2 * 64 * 8];    // 4 KB
    __shared__ unsigned short sd1[128 * 64];           // 16 KB (row-major bf16)
    __shared__ float sWd3[32];
    int t = threadIdx.x;
    for (int slot = t; slot < 2048; slot += 512) {     // Wdec: 8nt*4ks*64l
        int l = slot & 63, ntks = slot >> 6, ks = ntks & 3, nt = ntks >> 2;
        int krow = ks * 32 + ((l >> 4) << 3);
        int col = nt * 16 + (l & 15);
#pragma unroll
        for (int j = 0; j < 8; ++j)
            sBdec[slot * 8 + j] = f2bf(Wdec[(krow + j) * 128 + col]);
    }
    for (int slot = t; slot < 1024; slot += 512) {     // Wd1: 4nt*4ks*64l
        int l = slot & 63, ntks = slot >> 6, ks = ntks & 3, nt = ntks >> 2;
        int krow = ks * 32 + ((l >> 4) << 3);
        int col = nt * 16 + (l & 15);
#pragma unroll
        for (int j = 0; j < 8; ++j)
            sBd1[slot * 8 + j] = f2bf(Wd1[(krow + j) * 64 + col]);
    }
    if (t < 256) {                                     // Wd2: 2nt*2ks*64l
        int slot = t;
        int l = slot & 63, ntks = slot >> 6, ks = ntks & 1, nt = ntks >> 1;
        int krow = ks * 32 + ((l >> 4) << 3);
        int col = nt * 16 + (l & 15);
#pragma unroll
        for (int j = 0; j < 8; ++j)
            sBd2[slot * 8 + j] = f2bf(Wd2[(krow + j) * 32 + col]);
    }
    if (t < 32) sWd3[t] = Wd3[t];
    __syncthreads();

    int w = t >> 6, lane = t & 63;
    int base = blockIdx.x * 128 + w * 16;
    int arow = base + (lane & 15);
    int acl = arow < N ? arow : 0;
    const unsigned short* ap = enc16 + (long)acl * 128 + ((lane >> 4) << 3);

    f32x4 accR[8], accD1[4];
#pragma unroll
    for (int i = 0; i < 8; ++i) accR[i] = (f32x4){0.f, 0.f, 0.f, 0.f};
#pragma unroll
    for (int i = 0; i < 4; ++i) accD1[i] = (f32x4){0.f, 0.f, 0.f, 0.f};
#pragma unroll
    for (int ks = 0; ks < 4; ++ks) {
        bh8 a = *(const bh8*)(ap + ks * 32);
#pragma unroll
        for (int nt = 0; nt < 8; ++nt) {
            bh8 b = *(const bh8*)&sBdec[((nt * 4 + ks) * 64 + lane) * 8];
            accR[nt] = __builtin_amdgcn_mfma_f32_16x16x32_bf16(a, b, accR[nt], 0, 0, 0);
        }
#pragma unroll
        for (int nt = 0; nt < 4; ++nt) {
            bh8 b = *(const bh8*)&sBd1[((nt * 4 + ks) * 64 + lane) * 8];
            accD1[nt] = __builtin_amdgcn_mfma_f32_16x16x32_bf16(a, b, accD1[nt], 0, 0, 0);
        }
    }
    int rb = base + ((lane >> 4) << 2);
#pragma unroll
    for (int nt = 0; nt < 8; ++nt) {
        int col = nt * 16 + (lane & 15);
        float bcol = bdec[col];
#pragma unroll
        for (int r = 0; r < 4; ++r) {
            int grow = rb + r;
            if (grow < N)
                recon[(long)grow * 128 + col] = fmaxf(accR[nt][r] + bcol, 0.f);
        }
    }
    int lrb = w * 16 + ((lane >> 4) << 2);
#pragma unroll
    for (int nt = 0; nt < 4; ++nt) {
        int col = nt * 16 + (lane & 15);
        float bcol = bd1[col];
#pragma unroll
        for (int r = 0; r < 4; ++r)
            sd1[(lrb + r) * 64 + col] = f2bf(fmaxf(accD1[nt][r] + bcol, 0.f));
    }
    __syncthreads();
    f32x4 accD2[2];
    accD2[0] = (f32x4){0.f, 0.f, 0.f, 0.f};
    accD2[1] = (f32x4){0.f, 0.f, 0.f, 0.f};
#pragma unroll
    for (int ks = 0; ks < 2; ++ks) {
        bh8 a = *(const bh8*)&sd1[(w * 16 + (lane & 15)) * 64 + ks * 32 + ((lane >> 4) << 3)];
#pragma unroll
        for (int nt = 0; nt < 2; ++nt) {
            bh8 b = *(const bh8*)&sBd2[((nt * 2 + ks) * 64 + lane) * 8];
            accD2[nt] = __builtin_amdgcn_mfma_f32_16x16x32_bf16(a, b, accD2[nt], 0, 0, 0);
        }
    }
    float b2a = bd2[lane & 15], b2b = bd2[16 + (lane & 15)];
    float w3a = sWd3[lane & 15], w3b = sWd3[16 + (lane & 15)];
    float b3 = bd3[0];
#pragma unroll
    for (int r = 0; r < 4; ++r) {
        float v = w3a / (1.f + __expf(-(accD2[0][r] + b2a)))
                + w3b / (1.f + __expf(-(accD2[1][r] + b2b)));
        v += __shfl_xor(v, 1); v += __shfl_xor(v, 2);
        v += __shfl_xor(v, 4); v += __shfl_xor(v, 8);
        int grow = rb + r;
        if ((lane & 15) == 0 && grow < N) disc[grow] = v + b3;
    }
}

extern "C" void kernel_launch(void* const* d_in, const int* in_sizes, int n_in,
                              void* d_out, int out_size, void* d_ws, size_t ws_size,
                              hipStream_t stream)
{
    const float* features = (const float*)d_in[0];
    const void*  edges    = d_in[1];
    const int*   mask     = (const int*)d_in[2];
    const float* W_gat1 = (const float*)d_in[3];
    const float* a_src1 = (const float*)d_in[4];
    const float* a_dst1 = (const float*)d_in[5];
    const float* b_gat1 = (const float*)d_in[6];
    const float* W_gat2 = (const float*)d_in[7];
    const float* a_src2 = (const float*)d_in[8];
    const float* a_dst2 = (const float*)d_in[9];
    const float* b_gat2 = (const float*)d_in[10];
    const float* W_gcn1 = (const float*)d_in[11];
    const float* b_gcn1 = (const float*)d_in[12];
    const float* W_gcn2 = (const float*)d_in[13];
    const float* b_gcn2 = (const float*)d_in[14];
    const float* W_dec  = (const float*)d_in[15];
    const float* b_dec  = (const float*)d_in[16];
    const float* W_d1   = (const float*)d_in[17];
    const float* b_d1   = (const float*)d_in[18];
    const float* W_d2   = (const float*)d_in[19];
    const float* b_d2   = (const float*)d_in[20];
    const float* W_d3   = (const float*)d_in[21];
    const float* b_d3   = (const float*)d_in[22];

    const int  N = in_sizes[0] / 128;
    const long E = (long)in_sizes[1] / 2;

    size_t nP = ((size_t)N + 255) & ~(size_t)255;
    size_t eP = ((size_t)E + 255) & ~(size_t)255;
    int*   deg       = (int*)d_ws;
    int*   offs      = deg + nP;             // uses N+1
    int*   cursor    = offs + nP + 256;
    float* dinv      = (float*)(cursor + nP);
    float* a_s       = dinv + nP;
    float* a_d       = a_s + nP;
    int*   flag      = (int*)(a_d + nP);
    int*   blockSums = flag + 256;
    int*   blockOff  = blockSums + 1024;
    int*   csr       = blockOff + 1024;      // E
    unsigned short* h16 = (unsigned short*)(csr + eP);   // N*128 bf16
    unsigned* o16    = (unsigned*)(h16 + nP * 128);      // N*64 u32 (bf16 pairs)
    unsigned* enc16  = o16 + nP * 64;                    // N*64 u32 (bf16 pairs)

    hipMemsetAsync(deg, 0, nP * sizeof(int), stream);
    hipMemsetAsync(cursor, 0, nP * sizeof(int), stream);
    hipMemsetAsync(flag, 0, sizeof(int), stream);

    k_detect<<<16, 256, 0, stream>>>((const int*)edges, 2 * E, flag);

    unsigned eB = (unsigned)((E + 255) / 256);
    k_deg<<<eB, 256, 0, stream>>>(edges, E, flag, deg);

    int nbA = (N + 255) / 256;
    k_scanA<<<nbA, 256, 0, stream>>>(deg, N, offs, blockSums);
    k_scanB<<<1, 1024, 0, stream>>>(blockSums, nbA, blockOff);
    k_scanC<<<nbA, 256, 0, stream>>>(offs, blockOff, deg, dinv, N, E);
    int npp = (N + NSHARD - 1) / NSHARD;
    k_fill<<<eB * NSHARD, 256, 0, stream>>>(edges, E, flag, offs, cursor, csr, npp);

    unsigned aB = (unsigned)((N + 7) / 8);
    unsigned mB = (unsigned)((N + 127) / 128);

    k_denseM<0><<<mB, 512, 0, stream>>>(features, nullptr, mask,
                                        W_gat1, W_gcn1, a_src1, a_dst1, dinv,
                                        h16, a_s, a_d, N);
    k_agg<0><<<aB, 512, 0, stream>>>(offs, csr, a_s, a_d, dinv, h16,
                                     b_gat1, b_gcn1, nullptr, o16, N);
    k_denseM<1><<<mB, 512, 0, stream>>>(nullptr, (const unsigned short*)o16, nullptr,
                                        W_gat2, W_gcn2, a_src2, a_dst2, dinv,
                                        h16, a_s, a_d, N);
    float* out = (float*)d_out;
    float* enc = out + (long)N * 128;
    k_agg<1><<<aB, 512, 0, stream>>>(offs, csr, a_s, a_d, dinv, h16,
                                     b_gat2, b_gcn2, enc, enc16, N);
    k_dense3<<<mB, 512, 0, stream>>>((const unsigned short*)enc16,
                                     W_dec, b_dec, W_d1, b_d1,
                                     W_d2, b_d2, W_d3, b_d3,
                                     out, out + (long)N * 256, N);
}

// Round 18
// 395.943 us; speedup vs baseline: 1.3608x; 1.0127x over previous
//
#include <hip/hip_runtime.h>
#include <math.h>

// ---------------------------------------------------------------------------
// AFPNNet: masked features -> {2-layer GAT, 2-layer GCN} -> concat(encoded)
//          -> recon = relu(enc@Wdec+b), disc = (sigmoid(relu(enc@Wd1+b)@Wd2+b))@Wd3+b
// Outputs flat: recon [N*128] | encoded [N*128] | disc [N]
// h layout: interleaved BF16 [N][128]; csr stores BYTE offsets (src*256).
// LESSON (r4-r7, r14): ANY global weight load in a const-trip k-loop gets
//   serialized/hoisted -> weights MUST be staged in LDS. No exceptions.
// LESSON (r8/r9): k_fill write amplification = cross-XCD dirty-line
//   replication -> dst-shard by blockIdx&7.
// LESSON (r8-r16): VALU dense kernels plateau; MFMA ports broke it. D layout
//   col=lane&15,row=(lane>>4)*4+reg; A/B frag row/col=lane&15,k=(lane>>4)*8+j.
// r18: k_agg FETCH=188MB vs 25.6MB h16 working set -> streaming writes evict
//   h16 from L3. Non-temporal stores for never-re-read streams (enc f32,
//   recon, disc) + non-temporal loads for read-once csr. h16/o16/enc16 stay
//   cached (re-read by subsequent kernels).
// ---------------------------------------------------------------------------

#define INF_F __int_as_float(0x7f800000)
#define NSHARD 8

typedef __attribute__((ext_vector_type(8))) short bh8;
typedef __attribute__((ext_vector_type(4))) float f32x4;

__device__ __forceinline__ long edge_at(const void* p, int is64, long i) {
    if (is64) return (long)((const long long*)p)[i];
    return (long)((const int*)p)[i];
}

__device__ __forceinline__ unsigned short f2bf(float f) {   // RNE f32->bf16
    unsigned u = __float_as_uint(f);
    return (unsigned short)((u + 0x7FFFu + ((u >> 16) & 1u)) >> 16);
}
__device__ __forceinline__ float bflo(unsigned p) { return __uint_as_float(p << 16); }
__device__ __forceinline__ float bfhi(unsigned p) { return __uint_as_float(p & 0xFFFF0000u); }
__device__ __forceinline__ unsigned pk2bf(float a, float b) {
    return (unsigned)f2bf(a) | ((unsigned)f2bf(b) << 16);
}

__global__ void k_detect(const int* ew, long words, int* flag) {
    long t = (long)blockIdx.x * blockDim.x + threadIdx.x;
    long stride = words / 8192; if (stride < 1) stride = 1;
    long w = 2 * (t * stride) + 1;
    if (t < 4096 && w < words) {
        if (ew[w] != 0) atomicOr(flag, 1);
    }
}

__global__ void k_deg(const void* edges, long E, const int* flag, int* deg) {
    long e = (long)blockIdx.x * blockDim.x + threadIdx.x;
    if (e >= E) return;
    int is64 = (*flag == 0);
    int d = (int)edge_at(edges, is64, E + e);
    atomicAdd(&deg[d], 1);
}

__global__ void k_scanA(const int* deg, int N, int* offs, int* blockSums) {
    __shared__ int s[256];
    int t = threadIdx.x;
    int i = blockIdx.x * 256 + t;
    int v = (i < N) ? deg[i] : 0;
    s[t] = v;
    for (int off = 1; off < 256; off <<= 1) {
        __syncthreads();
        int u = (t >= off) ? s[t - off] : 0;
        __syncthreads();
        s[t] += u;
    }
    __syncthreads();
    if (i < N) offs[i] = s[t] - v;
    if (t == 255) blockSums[blockIdx.x] = s[255];
}

__global__ void k_scanB(const int* blockSums, int nb, int* blockOff) {
    __shared__ int s[1024];
    int t = threadIdx.x;
    int v = (t < nb) ? blockSums[t] : 0;
    s[t] = v;
    for (int off = 1; off < 1024; off <<= 1) {
        __syncthreads();
        int u = (t >= off) ? s[t - off] : 0;
        __syncthreads();
        s[t] += u;
    }
    __syncthreads();
    if (t < nb) blockOff[t] = s[t] - v;
}

__global__ void k_scanC(int* offs, const int* blockOff, const int* deg,
                        float* dinv, int N, long E) {
    int i = blockIdx.x * 256 + threadIdx.x;
    if (i < N) {
        offs[i] += blockOff[i >> 8];
        int dg = deg[i];
        dinv[i] = dg > 0 ? rsqrtf((float)dg) : 0.0f;
    }
    if (i == 0) offs[N] = (int)E;
}

// XCD-sharded CSR fill (see header LESSON r8/r9).
__global__ void k_fill(const void* edges, long E, const int* flag,
                       const int* offs, int* cursor, int* csr_src, int npp) {
    int bid = blockIdx.x;
    int shard = bid & (NSHARD - 1);
    long e = (long)(bid >> 3) * blockDim.x + threadIdx.x;
    if (e >= E) return;
    int is64 = (*flag == 0);
    int d = (int)edge_at(edges, is64, E + e);
    if (d / npp != shard) return;
    int s = (int)edge_at(edges, is64, e);
    int pos = offs[d] + atomicAdd(&cursor[d], 1);
    csr_src[pos] = s << 8;                 // byte offset into [N][128] bf16 rows
}

// Unified MFMA dense layer (mfma_f32_16x16x32_bf16), 128 nodes/block, 8 waves.
template <int MODE>
__global__ __launch_bounds__(512) void k_denseM(
    const float* __restrict__ xf, const unsigned short* __restrict__ a16,
    const int* __restrict__ mask,
    const float* __restrict__ Wa, const float* __restrict__ Wg,
    const float* __restrict__ aSrc, const float* __restrict__ aDst,
    const float* __restrict__ dinv,
    unsigned short* __restrict__ h16,
    float* __restrict__ a_s, float* __restrict__ a_d, int N)
{
    __shared__ unsigned short sB[8 * 4 * 64 * 8];      // 32 KB B-fragments
    __shared__ float sAs[64], sAd[64];
    int t = threadIdx.x;
    for (int slot = t; slot < 2048; slot += 512) {     // nt(8) x ks(4) x lane(64)
        int l = slot & 63, ntks = slot >> 6, ks = ntks & 3, nt = ntks >> 2;
        int col = nt * 16 + (l & 15);
        int kbase = ks * 32 + ((l >> 4) << 3);
#pragma unroll
        for (int j = 0; j < 8; ++j) {
            int k = kbase + j;
            float v;
            if (MODE == 0) {
                v = (col < 64) ? Wa[k * 64 + col] : Wg[k * 64 + (col - 64)];
            } else {
                if (col < 64) v = (k < 64) ? Wa[k * 64 + col] : 0.f;
                else          v = (k >= 64) ? Wg[(k - 64) * 64 + (col - 64)] : 0.f;
            }
            sB[slot * 8 + j] = f2bf(v);
        }
    }
    if (t < 64) { sAs[t] = aSrc[t]; sAd[t] = aDst[t]; }
    __syncthreads();

    int w = t >> 6, lane = t & 63;
    int base = blockIdx.x * 128 + w * 16;
    int arow = base + (lane & 15);
    int acl = arow < N ? arow : 0;

    bh8 afr[4];
    if (MODE == 0) {
        float msk = (arow < N && mask[acl] != 1) ? 1.f : 0.f;
        const float* ap = xf + (long)acl * 128 + ((lane >> 4) << 3);
#pragma unroll
        for (int ks = 0; ks < 4; ++ks) {
            float4 u0 = *(const float4*)(ap + ks * 32);
            float4 u1 = *(const float4*)(ap + ks * 32 + 4);
            union { bh8 v; unsigned u4[4]; } cv;
            cv.u4[0] = pk2bf(u0.x * msk, u0.y * msk);
            cv.u4[1] = pk2bf(u0.z * msk, u0.w * msk);
            cv.u4[2] = pk2bf(u1.x * msk, u1.y * msk);
            cv.u4[3] = pk2bf(u1.z * msk, u1.w * msk);
            afr[ks] = cv.v;
        }
    } else {
        const unsigned short* ap = a16 + (long)acl * 128 + ((lane >> 4) << 3);
#pragma unroll
        for (int ks = 0; ks < 4; ++ks) afr[ks] = *(const bh8*)(ap + ks * 32);
    }

    f32x4 acc[8];
#pragma unroll
    for (int i = 0; i < 8; ++i) acc[i] = (f32x4){0.f, 0.f, 0.f, 0.f};
#pragma unroll
    for (int ks = 0; ks < 4; ++ks) {
#pragma unroll
        for (int nt = 0; nt < 8; ++nt) {
            bh8 b = *(const bh8*)&sB[((nt * 4 + ks) * 64 + lane) * 8];
            acc[nt] = __builtin_amdgcn_mfma_f32_16x16x32_bf16(afr[ks], b, acc[nt], 0, 0, 0);
        }
    }

    int rb = base + ((lane >> 4) << 2);
    float dvr[4];
#pragma unroll
    for (int r = 0; r < 4; ++r) dvr[r] = (rb + r < N) ? dinv[rb + r] : 0.f;

    float pa[4] = {0.f, 0.f, 0.f, 0.f}, pd[4] = {0.f, 0.f, 0.f, 0.f};
#pragma unroll
    for (int nt = 0; nt < 4; ++nt) {
        float as = sAs[nt * 16 + (lane & 15)];
        float ad = sAd[nt * 16 + (lane & 15)];
#pragma unroll
        for (int r = 0; r < 4; ++r) {
            pa[r] = fmaf(acc[nt][r], as, pa[r]);
            pd[r] = fmaf(acc[nt][r], ad, pd[r]);
        }
    }
#pragma unroll
    for (int r = 0; r < 4; ++r) {
#pragma unroll
        for (int off = 8; off; off >>= 1) {
            pa[r] += __shfl_xor(pa[r], off);
            pd[r] += __shfl_xor(pd[r], off);
        }
        int grow = rb + r;
        if ((lane & 15) == 0 && grow < N) { a_s[grow] = pa[r]; a_d[grow] = pd[r]; }
    }
#pragma unroll
    for (int nt = 0; nt < 8; ++nt) {
        int col = nt * 16 + (lane & 15);
        bool gcn = nt >= 4;
#pragma unroll
        for (int r = 0; r < 4; ++r) {
            int grow = rb + r;
            if (grow < N) {
                float v = acc[nt][r];
                if (gcn) v *= dvr[r];
                h16[(long)grow * 128 + col] = f2bf(v);
            }
        }
    }
}

// Fused aggregation, wave per dst node. h rows bf16. MODE 0: writes o16 only.
// MODE 1: writes f32 enc (non-temporal; final output) + enc16 (cached).
template <int MODE>
__global__ __launch_bounds__(512) void k_agg(
    const int* __restrict__ offs, const int* __restrict__ csr,
    const float* __restrict__ a_s, const float* __restrict__ a_d,
    const float* __restrict__ dinv,
    const unsigned short* __restrict__ h16,
    const float* __restrict__ b_a, const float* __restrict__ b_g,
    float* __restrict__ out, unsigned* __restrict__ o16, int N)
{
    int node = blockIdx.x * 8 + (threadIdx.x >> 6);
    int lane = threadIdx.x & 63;
    if (node >= N) return;
    int p0 = offs[node], p1 = offs[node + 1];
    int deg = p1 - p0;
    float adst = a_d[node];
    float dv = dinv[node];
    bool gat = lane < 32;
    const char* hb = (const char*)h16 + lane * 4;

    float2 res = make_float2(0.f, 0.f);
    if (deg > 0 && deg <= 64) {
        int soff = (lane < deg) ? __builtin_nontemporal_load(&csr[p0 + lane]) : 0;
        float att = -INF_F;
        if (lane < deg) {
            float a = a_s[soff >> 8] + adst;
            att = a >= 0.f ? a : 0.2f * a;
        }
        float m = att;
#pragma unroll
        for (int off = 32; off; off >>= 1) m = fmaxf(m, __shfl_xor(m, off));
        float w = (lane < deg) ? __expf(att - m) : 0.f;
        float den = w;
#pragma unroll
        for (int off = 32; off; off >>= 1) den += __shfl_xor(den, off);
        float coef = w / den;

        float2 a0 = make_float2(0.f, 0.f), a1 = a0, a2 = a0, a3 = a0;
        int e = 0;
        for (; e + 4 <= deg; e += 4) {
            int o0 = __shfl(soff, e),     o1 = __shfl(soff, e + 1);
            int o2 = __shfl(soff, e + 2), o3 = __shfl(soff, e + 3);
            float c0 = __shfl(coef, e),     c1 = __shfl(coef, e + 1);
            float c2 = __shfl(coef, e + 2), c3 = __shfl(coef, e + 3);
            unsigned v0 = *(const unsigned*)(hb + o0);
            unsigned v1 = *(const unsigned*)(hb + o1);
            unsigned v2 = *(const unsigned*)(hb + o2);
            unsigned v3 = *(const unsigned*)(hb + o3);
            float w0 = gat ? c0 : 1.f, w1 = gat ? c1 : 1.f;
            float w2 = gat ? c2 : 1.f, w3 = gat ? c3 : 1.f;
            a0.x = fmaf(bflo(v0), w0, a0.x); a0.y = fmaf(bfhi(v0), w0, a0.y);
            a1.x = fmaf(bflo(v1), w1, a1.x); a1.y = fmaf(bfhi(v1), w1, a1.y);
            a2.x = fmaf(bflo(v2), w2, a2.x); a2.y = fmaf(bfhi(v2), w2, a2.y);
            a3.x = fmaf(bflo(v3), w3, a3.x); a3.y = fmaf(bfhi(v3), w3, a3.y);
        }
        for (; e < deg; ++e) {
            int oe = __shfl(soff, e);
            float ce = __shfl(coef, e);
            unsigned v = *(const unsigned*)(hb + oe);
            float we = gat ? ce : 1.f;
            a0.x = fmaf(bflo(v), we, a0.x); a0.y = fmaf(bfhi(v), we, a0.y);
        }
        res.x = (a0.x + a1.x) + (a2.x + a3.x);
        res.y = (a0.y + a1.y) + (a2.y + a3.y);
    } else if (deg > 64) {
        float m = -INF_F, den = 0.f;
        float2 aa = make_float2(0.f, 0.f);
        for (int p = p0; p < p1; ++p) {
            int soff = csr[p];
            float a = a_s[soff >> 8] + adst;
            float att = a >= 0.f ? a : 0.2f * a;
            float mn = fmaxf(m, att);
            float r = __expf(m - mn);
            float w = __expf(att - mn);
            den = den * r + w;
            unsigned v = *(const unsigned*)(hb + soff);
            float reff = gat ? r : 1.f, weff = gat ? w : 1.f;
            aa.x = fmaf(aa.x, reff, weff * bflo(v));
            aa.y = fmaf(aa.y, reff, weff * bfhi(v));
            m = mn;
        }
        if (gat) { res.x = aa.x / den; res.y = aa.y / den; }
        else     { res = aa; }
    }

    int col = lane * 2;
    float2 ov;
    if (gat) {
        ov.x = res.x + b_a[col];
        ov.y = res.y + b_a[col + 1];
        if (MODE == 0) {
            ov.x = ov.x > 0.f ? ov.x : (__expf(ov.x) - 1.f);
            ov.y = ov.y > 0.f ? ov.y : (__expf(ov.y) - 1.f);
        }
    } else {
        ov.x = dv * res.x + b_g[col - 64];
        ov.y = dv * res.y + b_g[col - 63];
        if (MODE == 0) {
            ov.x = fmaxf(ov.x, 0.f);
            ov.y = fmaxf(ov.y, 0.f);
        }
    }
    if (MODE == 1) {
        // final output, never re-read on device -> bypass cache retention
        __builtin_nontemporal_store(ov.x, &out[(long)node * 128 + col]);
        __builtin_nontemporal_store(ov.y, &out[(long)node * 128 + col + 1]);
    }
    o16[(long)node * 64 + lane] = pk2bf(ov.x, ov.y);
}

// Fused decoder + discriminator on MATRIX cores (r16; recon/disc stores NT).
__global__ __launch_bounds__(512) void k_dense3(
    const unsigned short* __restrict__ enc16,
    const float* __restrict__ Wdec, const float* __restrict__ bdec,
    const float* __restrict__ Wd1, const float* __restrict__ bd1,
    const float* __restrict__ Wd2, const float* __restrict__ bd2,
    const float* __restrict__ Wd3, const float* __restrict__ bd3,
    float* __restrict__ recon, float* __restrict__ disc, int N)
{
    __shared__ unsigned short sBdec[8 * 4 * 64 * 8];   // 32 KB
    __shared__ unsigned short sBd1[4 * 4 * 64 * 8];    // 16 KB
    __shared__ unsigned short sBd2[2 * 2 * 64 * 8];    // 4 KB
    __shared__ unsigned short sd1[128 * 64];           // 16 KB (row-major bf16)
    __shared__ float sWd3[32];
    int t = threadIdx.x;
    for (int slot = t; slot < 2048; slot += 512) {     // Wdec: 8nt*4ks*64l
        int l = slot & 63, ntks = slot >> 6, ks = ntks & 3, nt = ntks >> 2;
        int krow = ks * 32 + ((l >> 4) << 3);
        int col = nt * 16 + (l & 15);
#pragma unroll
        for (int j = 0; j < 8; ++j)
            sBdec[slot * 8 + j] = f2bf(Wdec[(krow + j) * 128 + col]);
    }
    for (int slot = t; slot < 1024; slot += 512) {     // Wd1: 4nt*4ks*64l
        int l = slot & 63, ntks = slot >> 6, ks = ntks & 3, nt = ntks >> 2;
        int krow = ks * 32 + ((l >> 4) << 3);
        int col = nt * 16 + (l & 15);
#pragma unroll
        for (int j = 0; j < 8; ++j)
            sBd1[slot * 8 + j] = f2bf(Wd1[(krow + j) * 64 + col]);
    }
    if (t < 256) {                                     // Wd2: 2nt*2ks*64l
        int slot = t;
        int l = slot & 63, ntks = slot >> 6, ks = ntks & 1, nt = ntks >> 1;
        int krow = ks * 32 + ((l >> 4) << 3);
        int col = nt * 16 + (l & 15);
#pragma unroll
        for (int j = 0; j < 8; ++j)
            sBd2[slot * 8 + j] = f2bf(Wd2[(krow + j) * 32 + col]);
    }
    if (t < 32) sWd3[t] = Wd3[t];
    __syncthreads();

    int w = t >> 6, lane = t & 63;
    int base = blockIdx.x * 128 + w * 16;
    int arow = base + (lane & 15);
    int acl = arow < N ? arow : 0;
    const unsigned short* ap = enc16 + (long)acl * 128 + ((lane >> 4) << 3);

    f32x4 accR[8], accD1[4];
#pragma unroll
    for (int i = 0; i < 8; ++i) accR[i] = (f32x4){0.f, 0.f, 0.f, 0.f};
#pragma unroll
    for (int i = 0; i < 4; ++i) accD1[i] = (f32x4){0.f, 0.f, 0.f, 0.f};
#pragma unroll
    for (int ks = 0; ks < 4; ++ks) {
        bh8 a = *(const bh8*)(ap + ks * 32);
#pragma unroll
        for (int nt = 0; nt < 8; ++nt) {
            bh8 b = *(const bh8*)&sBdec[((nt * 4 + ks) * 64 + lane) * 8];
            accR[nt] = __builtin_amdgcn_mfma_f32_16x16x32_bf16(a, b, accR[nt], 0, 0, 0);
        }
#pragma unroll
        for (int nt = 0; nt < 4; ++nt) {
            bh8 b = *(const bh8*)&sBd1[((nt * 4 + ks) * 64 + lane) * 8];
            accD1[nt] = __builtin_amdgcn_mfma_f32_16x16x32_bf16(a, b, accD1[nt], 0, 0, 0);
        }
    }
    int rb = base + ((lane >> 4) << 2);
#pragma unroll
    for (int nt = 0; nt < 8; ++nt) {
        int col = nt * 16 + (lane & 15);
        float bcol = bdec[col];
#pragma unroll
        for (int r = 0; r < 4; ++r) {
            int grow = rb + r;
            if (grow < N)
                __builtin_nontemporal_store(fmaxf(accR[nt][r] + bcol, 0.f),
                                            &recon[(long)grow * 128 + col]);
        }
    }
    int lrb = w * 16 + ((lane >> 4) << 2);
#pragma unroll
    for (int nt = 0; nt < 4; ++nt) {
        int col = nt * 16 + (lane & 15);
        float bcol = bd1[col];
#pragma unroll
        for (int r = 0; r < 4; ++r)
            sd1[(lrb + r) * 64 + col] = f2bf(fmaxf(accD1[nt][r] + bcol, 0.f));
    }
    __syncthreads();
    f32x4 accD2[2];
    accD2[0] = (f32x4){0.f, 0.f, 0.f, 0.f};
    accD2[1] = (f32x4){0.f, 0.f, 0.f, 0.f};
#pragma unroll
    for (int ks = 0; ks < 2; ++ks) {
        bh8 a = *(const bh8*)&sd1[(w * 16 + (lane & 15)) * 64 + ks * 32 + ((lane >> 4) << 3)];
#pragma unroll
        for (int nt = 0; nt < 2; ++nt) {
            bh8 b = *(const bh8*)&sBd2[((nt * 2 + ks) * 64 + lane) * 8];
            accD2[nt] = __builtin_amdgcn_mfma_f32_16x16x32_bf16(a, b, accD2[nt], 0, 0, 0);
        }
    }
    float b2a = bd2[lane & 15], b2b = bd2[16 + (lane & 15)];
    float w3a = sWd3[lane & 15], w3b = sWd3[16 + (lane & 15)];
    float b3 = bd3[0];
#pragma unroll
    for (int r = 0; r < 4; ++r) {
        float v = w3a / (1.f + __expf(-(accD2[0][r] + b2a)))
                + w3b / (1.f + __expf(-(accD2[1][r] + b2b)));
        v += __shfl_xor(v, 1); v += __shfl_xor(v, 2);
        v += __shfl_xor(v, 4); v += __shfl_xor(v, 8);
        int grow = rb + r;
        if ((lane & 15) == 0 && grow < N)
            __builtin_nontemporal_store(v + b3, &disc[grow]);
    }
}

extern "C" void kernel_launch(void* const* d_in, const int* in_sizes, int n_in,
                              void* d_out, int out_size, void* d_ws, size_t ws_size,
                              hipStream_t stream)
{
    const float* features = (const float*)d_in[0];
    const void*  edges    = d_in[1];
    const int*   mask     = (const int*)d_in[2];
    const float* W_gat1 = (const float*)d_in[3];
    const float* a_src1 = (const float*)d_in[4];
    const float* a_dst1 = (const float*)d_in[5];
    const float* b_gat1 = (const float*)d_in[6];
    const float* W_gat2 = (const float*)d_in[7];
    const float* a_src2 = (const float*)d_in[8];
    const float* a_dst2 = (const float*)d_in[9];
    const float* b_gat2 = (const float*)d_in[10];
    const float* W_gcn1 = (const float*)d_in[11];
    const float* b_gcn1 = (const float*)d_in[12];
    const float* W_gcn2 = (const float*)d_in[13];
    const float* b_gcn2 = (const float*)d_in[14];
    const float* W_dec  = (const float*)d_in[15];
    const float* b_dec  = (const float*)d_in[16];
    const float* W_d1   = (const float*)d_in[17];
    const float* b_d1   = (const float*)d_in[18];
    const float* W_d2   = (const float*)d_in[19];
    const float* b_d2   = (const float*)d_in[20];
    const float* W_d3   = (const float*)d_in[21];
    const float* b_d3   = (const float*)d_in[22];

    const int  N = in_sizes[0] / 128;
    const long E = (long)in_sizes[1] / 2;

    size_t nP = ((size_t)N + 255) & ~(size_t)255;
    size_t eP = ((size_t)E + 255) & ~(size_t)255;
    int*   deg       = (int*)d_ws;
    int*   offs      = deg + nP;             // uses N+1
    int*   cursor    = offs + nP + 256;
    float* dinv      = (float*)(cursor + nP);
    float* a_s       = dinv + nP;
    float* a_d       = a_s + nP;
    int*   flag      = (int*)(a_d + nP);
    int*   blockSums = flag + 256;
    int*   blockOff  = blockSums + 1024;
    int*   csr       = blockOff + 1024;      // E
    unsigned short* h16 = (unsigned short*)(csr + eP);   // N*128 bf16
    unsigned* o16    = (unsigned*)(h16 + nP * 128);      // N*64 u32 (bf16 pairs)
    unsigned* enc16  = o16 + nP * 64;                    // N*64 u32 (bf16 pairs)

    hipMemsetAsync(deg, 0, nP * sizeof(int), stream);
    hipMemsetAsync(cursor, 0, nP * sizeof(int), stream);
    hipMemsetAsync(flag, 0, sizeof(int), stream);

    k_detect<<<16, 256, 0, stream>>>((const int*)edges, 2 * E, flag);

    unsigned eB = (unsigned)((E + 255) / 256);
    k_deg<<<eB, 256, 0, stream>>>(edges, E, flag, deg);

    int nbA = (N + 255) / 256;
    k_scanA<<<nbA, 256, 0, stream>>>(deg, N, offs, blockSums);
    k_scanB<<<1, 1024, 0, stream>>>(blockSums, nbA, blockOff);
    k_scanC<<<nbA, 256, 0, stream>>>(offs, blockOff, deg, dinv, N, E);
    int npp = (N + NSHARD - 1) / NSHARD;
    k_fill<<<eB * NSHARD, 256, 0, stream>>>(edges, E, flag, offs, cursor, csr, npp);

    unsigned aB = (unsigned)((N + 7) / 8);
    unsigned mB = (unsigned)((N + 127) / 128);

    k_denseM<0><<<mB, 512, 0, stream>>>(features, nullptr, mask,
                                        W_gat1, W_gcn1, a_src1, a_dst1, dinv,
                                        h16, a_s, a_d, N);
    k_agg<0><<<aB, 512, 0, stream>>>(offs, csr, a_s, a_d, dinv, h16,
                                     b_gat1, b_gcn1, nullptr, o16, N);
    k_denseM<1><<<mB, 512, 0, stream>>>(nullptr, (const unsigned short*)o16, nullptr,
                                        W_gat2, W_gcn2, a_src2, a_dst2, dinv,
                                        h16, a_s, a_d, N);
    float* out = (float*)d_out;
    float* enc = out + (long)N * 128;
    k_agg<1><<<aB, 512, 0, stream>>>(offs, csr, a_s, a_d, dinv, h16,
                                     b_gat2, b_gcn2, enc, enc16, N);
    k_dense3<<<mB, 512, 0, stream>>>((const unsigned short*)enc16,
                                     W_dec, b_dec, W_d1, b_d1,
                                     W_d2, b_d2, W_d3, b_d3,
                                     out, out + (long)N * 256, N);
}

// Round 19
// 388.757 us; speedup vs baseline: 1.3860x; 1.0185x over previous
//
#include <hip/hip_runtime.h>
#include <math.h>

// ---------------------------------------------------------------------------
// AFPNNet: masked features -> {2-layer GAT, 2-layer GCN} -> concat(encoded)
//          -> recon = relu(enc@Wdec+b), disc = (sigmoid(relu(enc@Wd1+b)@Wd2+b))@Wd3+b
// Outputs flat: recon [N*128] | encoded [N*128] | disc [N]
// h layout: interleaved BF16 [N][128]; csr stores BYTE offsets (src*256).
// LESSON (r4-r7, r14): ANY global weight load in a const-trip k-loop gets
//   serialized/hoisted -> weights MUST be staged in LDS. No exceptions.
// LESSON (r8/r9): k_fill write amplification = cross-XCD dirty-line
//   replication -> dst-shard by blockIdx&7.
// LESSON (r8-r16): VALU dense kernels plateau; MFMA ports broke it. D layout
//   col=lane&15,row=(lane>>4)*4+reg; A/B frag row/col=lane&15,k=(lane>>4)*8+j.
// LESSON (r18): NT stores on final outputs (recon/disc/enc) help slightly;
//   NT load on csr REGRESSES (csr re-read by 2nd k_agg) -> reverted.
// r19: k_agg edge broadcasts __shfl(x,e) -> __builtin_amdgcn_readlane (e is
//   wave-uniform; shfl was emitting ds_bpermute = 2 DS-pipe ops/edge).
// ---------------------------------------------------------------------------

#define INF_F __int_as_float(0x7f800000)
#define NSHARD 8

typedef __attribute__((ext_vector_type(8))) short bh8;
typedef __attribute__((ext_vector_type(4))) float f32x4;

__device__ __forceinline__ long edge_at(const void* p, int is64, long i) {
    if (is64) return (long)((const long long*)p)[i];
    return (long)((const int*)p)[i];
}

__device__ __forceinline__ unsigned short f2bf(float f) {   // RNE f32->bf16
    unsigned u = __float_as_uint(f);
    return (unsigned short)((u + 0x7FFFu + ((u >> 16) & 1u)) >> 16);
}
__device__ __forceinline__ float bflo(unsigned p) { return __uint_as_float(p << 16); }
__device__ __forceinline__ float bfhi(unsigned p) { return __uint_as_float(p & 0xFFFF0000u); }
__device__ __forceinline__ unsigned pk2bf(float a, float b) {
    return (unsigned)f2bf(a) | ((unsigned)f2bf(b) << 16);
}

__global__ void k_detect(const int* ew, long words, int* flag) {
    long t = (long)blockIdx.x * blockDim.x + threadIdx.x;
    long stride = words / 8192; if (stride < 1) stride = 1;
    long w = 2 * (t * stride) + 1;
    if (t < 4096 && w < words) {
        if (ew[w] != 0) atomicOr(flag, 1);
    }
}

__global__ void k_deg(const void* edges, long E, const int* flag, int* deg) {
    long e = (long)blockIdx.x * blockDim.x + threadIdx.x;
    if (e >= E) return;
    int is64 = (*flag == 0);
    int d = (int)edge_at(edges, is64, E + e);
    atomicAdd(&deg[d], 1);
}

__global__ void k_scanA(const int* deg, int N, int* offs, int* blockSums) {
    __shared__ int s[256];
    int t = threadIdx.x;
    int i = blockIdx.x * 256 + t;
    int v = (i < N) ? deg[i] : 0;
    s[t] = v;
    for (int off = 1; off < 256; off <<= 1) {
        __syncthreads();
        int u = (t >= off) ? s[t - off] : 0;
        __syncthreads();
        s[t] += u;
    }
    __syncthreads();
    if (i < N) offs[i] = s[t] - v;
    if (t == 255) blockSums[blockIdx.x] = s[255];
}

__global__ void k_scanB(const int* blockSums, int nb, int* blockOff) {
    __shared__ int s[1024];
    int t = threadIdx.x;
    int v = (t < nb) ? blockSums[t] : 0;
    s[t] = v;
    for (int off = 1; off < 1024; off <<= 1) {
        __syncthreads();
        int u = (t >= off) ? s[t - off] : 0;
        __syncthreads();
        s[t] += u;
    }
    __syncthreads();
    if (t < nb) blockOff[t] = s[t] - v;
}

__global__ void k_scanC(int* offs, const int* blockOff, const int* deg,
                        float* dinv, int N, long E) {
    int i = blockIdx.x * 256 + threadIdx.x;
    if (i < N) {
        offs[i] += blockOff[i >> 8];
        int dg = deg[i];
        dinv[i] = dg > 0 ? rsqrtf((float)dg) : 0.0f;
    }
    if (i == 0) offs[N] = (int)E;
}

// XCD-sharded CSR fill (see header LESSON r8/r9).
__global__ void k_fill(const void* edges, long E, const int* flag,
                       const int* offs, int* cursor, int* csr_src, int npp) {
    int bid = blockIdx.x;
    int shard = bid & (NSHARD - 1);
    long e = (long)(bid >> 3) * blockDim.x + threadIdx.x;
    if (e >= E) return;
    int is64 = (*flag == 0);
    int d = (int)edge_at(edges, is64, E + e);
    if (d / npp != shard) return;
    int s = (int)edge_at(edges, is64, e);
    int pos = offs[d] + atomicAdd(&cursor[d], 1);
    csr_src[pos] = s << 8;                 // byte offset into [N][128] bf16 rows
}

// Unified MFMA dense layer (mfma_f32_16x16x32_bf16), 128 nodes/block, 8 waves.
template <int MODE>
__global__ __launch_bounds__(512) void k_denseM(
    const float* __restrict__ xf, const unsigned short* __restrict__ a16,
    const int* __restrict__ mask,
    const float* __restrict__ Wa, const float* __restrict__ Wg,
    const float* __restrict__ aSrc, const float* __restrict__ aDst,
    const float* __restrict__ dinv,
    unsigned short* __restrict__ h16,
    float* __restrict__ a_s, float* __restrict__ a_d, int N)
{
    __shared__ unsigned short sB[8 * 4 * 64 * 8];      // 32 KB B-fragments
    __shared__ float sAs[64], sAd[64];
    int t = threadIdx.x;
    for (int slot = t; slot < 2048; slot += 512) {     // nt(8) x ks(4) x lane(64)
        int l = slot & 63, ntks = slot >> 6, ks = ntks & 3, nt = ntks >> 2;
        int col = nt * 16 + (l & 15);
        int kbase = ks * 32 + ((l >> 4) << 3);
#pragma unroll
        for (int j = 0; j < 8; ++j) {
            int k = kbase + j;
            float v;
            if (MODE == 0) {
                v = (col < 64) ? Wa[k * 64 + col] : Wg[k * 64 + (col - 64)];
            } else {
                if (col < 64) v = (k < 64) ? Wa[k * 64 + col] : 0.f;
                else          v = (k >= 64) ? Wg[(k - 64) * 64 + (col - 64)] : 0.f;
            }
            sB[slot * 8 + j] = f2bf(v);
        }
    }
    if (t < 64) { sAs[t] = aSrc[t]; sAd[t] = aDst[t]; }
    __syncthreads();

    int w = t >> 6, lane = t & 63;
    int base = blockIdx.x * 128 + w * 16;
    int arow = base + (lane & 15);
    int acl = arow < N ? arow : 0;

    bh8 afr[4];
    if (MODE == 0) {
        float msk = (arow < N && mask[acl] != 1) ? 1.f : 0.f;
        const float* ap = xf + (long)acl * 128 + ((lane >> 4) << 3);
#pragma unroll
        for (int ks = 0; ks < 4; ++ks) {
            float4 u0 = *(const float4*)(ap + ks * 32);
            float4 u1 = *(const float4*)(ap + ks * 32 + 4);
            union { bh8 v; unsigned u4[4]; } cv;
            cv.u4[0] = pk2bf(u0.x * msk, u0.y * msk);
            cv.u4[1] = pk2bf(u0.z * msk, u0.w * msk);
            cv.u4[2] = pk2bf(u1.x * msk, u1.y * msk);
            cv.u4[3] = pk2bf(u1.z * msk, u1.w * msk);
            afr[ks] = cv.v;
        }
    } else {
        const unsigned short* ap = a16 + (long)acl * 128 + ((lane >> 4) << 3);
#pragma unroll
        for (int ks = 0; ks < 4; ++ks) afr[ks] = *(const bh8*)(ap + ks * 32);
    }

    f32x4 acc[8];
#pragma unroll
    for (int i = 0; i < 8; ++i) acc[i] = (f32x4){0.f, 0.f, 0.f, 0.f};
#pragma unroll
    for (int ks = 0; ks < 4; ++ks) {
#pragma unroll
        for (int nt = 0; nt < 8; ++nt) {
            bh8 b = *(const bh8*)&sB[((nt * 4 + ks) * 64 + lane) * 8];
            acc[nt] = __builtin_amdgcn_mfma_f32_16x16x32_bf16(afr[ks], b, acc[nt], 0, 0, 0);
        }
    }

    int rb = base + ((lane >> 4) << 2);
    float dvr[4];
#pragma unroll
    for (int r = 0; r < 4; ++r) dvr[r] = (rb + r < N) ? dinv[rb + r] : 0.f;

    float pa[4] = {0.f, 0.f, 0.f, 0.f}, pd[4] = {0.f, 0.f, 0.f, 0.f};
#pragma unroll
    for (int nt = 0; nt < 4; ++nt) {
        float as = sAs[nt * 16 + (lane & 15)];
        float ad = sAd[nt * 16 + (lane & 15)];
#pragma unroll
        for (int r = 0; r < 4; ++r) {
            pa[r] = fmaf(acc[nt][r], as, pa[r]);
            pd[r] = fmaf(acc[nt][r], ad, pd[r]);
        }
    }
#pragma unroll
    for (int r = 0; r < 4; ++r) {
#pragma unroll
        for (int off = 8; off; off >>= 1) {
            pa[r] += __shfl_xor(pa[r], off);
            pd[r] += __shfl_xor(pd[r], off);
        }
        int grow = rb + r;
        if ((lane & 15) == 0 && grow < N) { a_s[grow] = pa[r]; a_d[grow] = pd[r]; }
    }
#pragma unroll
    for (int nt = 0; nt < 8; ++nt) {
        int col = nt * 16 + (lane & 15);
        bool gcn = nt >= 4;
#pragma unroll
        for (int r = 0; r < 4; ++r) {
            int grow = rb + r;
            if (grow < N) {
                float v = acc[nt][r];
                if (gcn) v *= dvr[r];
                h16[(long)grow * 128 + col] = f2bf(v);
            }
        }
    }
}

// Fused aggregation, wave per dst node. h rows bf16. MODE 0: writes o16 only.
// MODE 1: writes f32 enc (non-temporal; final output) + enc16 (cached).
// Edge broadcasts use readlane (wave-uniform index) -> scalar, no DS-pipe ops.
template <int MODE>
__global__ __launch_bounds__(512) void k_agg(
    const int* __restrict__ offs, const int* __restrict__ csr,
    const float* __restrict__ a_s, const float* __restrict__ a_d,
    const float* __restrict__ dinv,
    const unsigned short* __restrict__ h16,
    const float* __restrict__ b_a, const float* __restrict__ b_g,
    float* __restrict__ out, unsigned* __restrict__ o16, int N)
{
    int node = blockIdx.x * 8 + (threadIdx.x >> 6);
    int lane = threadIdx.x & 63;
    if (node >= N) return;
    int p0 = offs[node], p1 = offs[node + 1];
    int deg = p1 - p0;
    float adst = a_d[node];
    float dv = dinv[node];
    bool gat = lane < 32;
    const char* hb = (const char*)h16 + lane * 4;

    float2 res = make_float2(0.f, 0.f);
    if (deg > 0 && deg <= 64) {
        int soff = (lane < deg) ? csr[p0 + lane] : 0;
        float att = -INF_F;
        if (lane < deg) {
            float a = a_s[soff >> 8] + adst;
            att = a >= 0.f ? a : 0.2f * a;
        }
        float m = att;
#pragma unroll
        for (int off = 32; off; off >>= 1) m = fmaxf(m, __shfl_xor(m, off));
        float w = (lane < deg) ? __expf(att - m) : 0.f;
        float den = w;
#pragma unroll
        for (int off = 32; off; off >>= 1) den += __shfl_xor(den, off);
        float coefl = w / den;
        int coefi = __float_as_int(coefl);

        float2 a0 = make_float2(0.f, 0.f), a1 = a0, a2 = a0, a3 = a0;
        int e = 0;
        for (; e + 4 <= deg; e += 4) {
            int o0 = __builtin_amdgcn_readlane(soff, e);
            int o1 = __builtin_amdgcn_readlane(soff, e + 1);
            int o2 = __builtin_amdgcn_readlane(soff, e + 2);
            int o3 = __builtin_amdgcn_readlane(soff, e + 3);
            float c0 = __int_as_float(__builtin_amdgcn_readlane(coefi, e));
            float c1 = __int_as_float(__builtin_amdgcn_readlane(coefi, e + 1));
            float c2 = __int_as_float(__builtin_amdgcn_readlane(coefi, e + 2));
            float c3 = __int_as_float(__builtin_amdgcn_readlane(coefi, e + 3));
            unsigned v0 = *(const unsigned*)(hb + o0);
            unsigned v1 = *(const unsigned*)(hb + o1);
            unsigned v2 = *(const unsigned*)(hb + o2);
            unsigned v3 = *(const unsigned*)(hb + o3);
            float w0 = gat ? c0 : 1.f, w1 = gat ? c1 : 1.f;
            float w2 = gat ? c2 : 1.f, w3 = gat ? c3 : 1.f;
            a0.x = fmaf(bflo(v0), w0, a0.x); a0.y = fmaf(bfhi(v0), w0, a0.y);
            a1.x = fmaf(bflo(v1), w1, a1.x); a1.y = fmaf(bfhi(v1), w1, a1.y);
            a2.x = fmaf(bflo(v2), w2, a2.x); a2.y = fmaf(bfhi(v2), w2, a2.y);
            a3.x = fmaf(bflo(v3), w3, a3.x); a3.y = fmaf(bfhi(v3), w3, a3.y);
        }
        for (; e < deg; ++e) {
            int oe = __builtin_amdgcn_readlane(soff, e);
            float ce = __int_as_float(__builtin_amdgcn_readlane(coefi, e));
            unsigned v = *(const unsigned*)(hb + oe);
            float we = gat ? ce : 1.f;
            a0.x = fmaf(bflo(v), we, a0.x); a0.y = fmaf(bfhi(v), we, a0.y);
        }
        res.x = (a0.x + a1.x) + (a2.x + a3.x);
        res.y = (a0.y + a1.y) + (a2.y + a3.y);
    } else if (deg > 64) {
        float m = -INF_F, den = 0.f;
        float2 aa = make_float2(0.f, 0.f);
        for (int p = p0; p < p1; ++p) {
            int soff = csr[p];
            float a = a_s[soff >> 8] + adst;
            float att = a >= 0.f ? a : 0.2f * a;
            float mn = fmaxf(m, att);
            float r = __expf(m - mn);
            float w = __expf(att - mn);
            den = den * r + w;
            unsigned v = *(const unsigned*)(hb + soff);
            float reff = gat ? r : 1.f, weff = gat ? w : 1.f;
            aa.x = fmaf(aa.x, reff, weff * bflo(v));
            aa.y = fmaf(aa.y, reff, weff * bfhi(v));
            m = mn;
        }
        if (gat) { res.x = aa.x / den; res.y = aa.y / den; }
        else     { res = aa; }
    }

    int col = lane * 2;
    float2 ov;
    if (gat) {
        ov.x = res.x + b_a[col];
        ov.y = res.y + b_a[col + 1];
        if (MODE == 0) {
            ov.x = ov.x > 0.f ? ov.x : (__expf(ov.x) - 1.f);
            ov.y = ov.y > 0.f ? ov.y : (__expf(ov.y) - 1.f);
        }
    } else {
        ov.x = dv * res.x + b_g[col - 64];
        ov.y = dv * res.y + b_g[col - 63];
        if (MODE == 0) {
            ov.x = fmaxf(ov.x, 0.f);
            ov.y = fmaxf(ov.y, 0.f);
        }
    }
    if (MODE == 1) {
        __builtin_nontemporal_store(ov.x, &out[(long)node * 128 + col]);
        __builtin_nontemporal_store(ov.y, &out[(long)node * 128 + col + 1]);
    }
    o16[(long)node * 64 + lane] = pk2bf(ov.x, ov.y);
}

// Fused decoder + discriminator on MATRIX cores (r16; recon/disc stores NT).
__global__ __launch_bounds__(512) void k_dense3(
    const unsigned short* __restrict__ enc16,
    const float* __restrict__ Wdec, const float* __restrict__ bdec,
    const float* __restrict__ Wd1, const float* __restrict__ bd1,
    const float* __restrict__ Wd2, const float* __restrict__ bd2,
    const float* __restrict__ Wd3, const float* __restrict__ bd3,
    float* __restrict__ recon, float* __restrict__ disc, int N)
{
    __shared__ unsigned short sBdec[8 * 4 * 64 * 8];   // 32 KB
    __shared__ unsigned short sBd1[4 * 4 * 64 * 8];    // 16 KB
    __shared__ unsigned short sBd2[2 * 2 * 64 * 8];    // 4 KB
    __shared__ unsigned short sd1[128 * 64];           // 16 KB (row-major bf16)
    __shared__ float sWd3[32];
    int t = threadIdx.x;
    for (int slot = t; slot < 2048; slot += 512) {     // Wdec: 8nt*4ks*64l
        int l = slot & 63, ntks = slot >> 6, ks = ntks & 3, nt = ntks >> 2;
        int krow = ks * 32 + ((l >> 4) << 3);
        int col = nt * 16 + (l & 15);
#pragma unroll
        for (int j = 0; j < 8; ++j)
            sBdec[slot * 8 + j] = f2bf(Wdec[(krow + j) * 128 + col]);
    }
    for (int slot = t; slot < 1024; slot += 512) {     // Wd1: 4nt*4ks*64l
        int l = slot & 63, ntks = slot >> 6, ks = ntks & 3, nt = ntks >> 2;
        int krow = ks * 32 + ((l >> 4) << 3);
        int col = nt * 16 + (l & 15);
#pragma unroll
        for (int j = 0; j < 8; ++j)
            sBd1[slot * 8 + j] = f2bf(Wd1[(krow + j) * 64 + col]);
    }
    if (t < 256) {                                     // Wd2: 2nt*2ks*64l
        int slot = t;
        int l = slot & 63, ntks = slot >> 6, ks = ntks & 1, nt = ntks >> 1;
        int krow = ks * 32 + ((l >> 4) << 3);
        int col = nt * 16 + (l & 15);
#pragma unroll
        for (int j = 0; j < 8; ++j)
            sBd2[slot * 8 + j] = f2bf(Wd2[(krow + j) * 32 + col]);
    }
    if (t < 32) sWd3[t] = Wd3[t];
    __syncthreads();

    int w = t >> 6, lane = t & 63;
    int base = blockIdx.x * 128 + w * 16;
    int arow = base + (lane & 15);
    int acl = arow < N ? arow : 0;
    const unsigned short* ap = enc16 + (long)acl * 128 + ((lane >> 4) << 3);

    f32x4 accR[8], accD1[4];
#pragma unroll
    for (int i = 0; i < 8; ++i) accR[i] = (f32x4){0.f, 0.f, 0.f, 0.f};
#pragma unroll
    for (int i = 0; i < 4; ++i) accD1[i] = (f32x4){0.f, 0.f, 0.f, 0.f};
#pragma unroll
    for (int ks = 0; ks < 4; ++ks) {
        bh8 a = *(const bh8*)(ap + ks * 32);
#pragma unroll
        for (int nt = 0; nt < 8; ++nt) {
            bh8 b = *(const bh8*)&sBdec[((nt * 4 + ks) * 64 + lane) * 8];
            accR[nt] = __builtin_amdgcn_mfma_f32_16x16x32_bf16(a, b, accR[nt], 0, 0, 0);
        }
#pragma unroll
        for (int nt = 0; nt < 4; ++nt) {
            bh8 b = *(const bh8*)&sBd1[((nt * 4 + ks) * 64 + lane) * 8];
            accD1[nt] = __builtin_amdgcn_mfma_f32_16x16x32_bf16(a, b, accD1[nt], 0, 0, 0);
        }
    }
    int rb = base + ((lane >> 4) << 2);
#pragma unroll
    for (int nt = 0; nt < 8; ++nt) {
        int col = nt * 16 + (lane & 15);
        float bcol = bdec[col];
#pragma unroll
        for (int r = 0; r < 4; ++r) {
            int grow = rb + r;
            if (grow < N)
                __builtin_nontemporal_store(fmaxf(accR[nt][r] + bcol, 0.f),
                                            &recon[(long)grow * 128 + col]);
        }
    }
    int lrb = w * 16 + ((lane >> 4) << 2);
#pragma unroll
    for (int nt = 0; nt < 4; ++nt) {
        int col = nt * 16 + (lane & 15);
        float bcol = bd1[col];
#pragma unroll
        for (int r = 0; r < 4; ++r)
            sd1[(lrb + r) * 64 + col] = f2bf(fmaxf(accD1[nt][r] + bcol, 0.f));
    }
    __syncthreads();
    f32x4 accD2[2];
    accD2[0] = (f32x4){0.f, 0.f, 0.f, 0.f};
    accD2[1] = (f32x4){0.f, 0.f, 0.f, 0.f};
#pragma unroll
    for (int ks = 0; ks < 2; ++ks) {
        bh8 a = *(const bh8*)&sd1[(w * 16 + (lane & 15)) * 64 + ks * 32 + ((lane >> 4) << 3)];
#pragma unroll
        for (int nt = 0; nt < 2; ++nt) {
            bh8 b = *(const bh8*)&sBd2[((nt * 2 + ks) * 64 + lane) * 8];
            accD2[nt] = __builtin_amdgcn_mfma_f32_16x16x32_bf16(a, b, accD2[nt], 0, 0, 0);
        }
    }
    float b2a = bd2[lane & 15], b2b = bd2[16 + (lane & 15)];
    float w3a = sWd3[lane & 15], w3b = sWd3[16 + (lane & 15)];
    float b3 = bd3[0];
#pragma unroll
    for (int r = 0; r < 4; ++r) {
        float v = w3a / (1.f + __expf(-(accD2[0][r] + b2a)))
                + w3b / (1.f + __expf(-(accD2[1][r] + b2b)));
        v += __shfl_xor(v, 1); v += __shfl_xor(v, 2);
        v += __shfl_xor(v, 4); v += __shfl_xor(v, 8);
        int grow = rb + r;
        if ((lane & 15) == 0 && grow < N)
            __builtin_nontemporal_store(v + b3, &disc[grow]);
    }
}

extern "C" void kernel_launch(void* const* d_in, const int* in_sizes, int n_in,
                              void* d_out, int out_size, void* d_ws, size_t ws_size,
                              hipStream_t stream)
{
    const float* features = (const float*)d_in[0];
    const void*  edges    = d_in[1];
    const int*   mask     = (const int*)d_in[2];
    const float* W_gat1 = (const float*)d_in[3];
    const float* a_src1 = (const float*)d_in[4];
    const float* a_dst1 = (const float*)d_in[5];
    const float* b_gat1 = (const float*)d_in[6];
    const float* W_gat2 = (const float*)d_in[7];
    const float* a_src2 = (const float*)d_in[8];
    const float* a_dst2 = (const float*)d_in[9];
    const float* b_gat2 = (const float*)d_in[10];
    const float* W_gcn1 = (const float*)d_in[11];
    const float* b_gcn1 = (const float*)d_in[12];
    const float* W_gcn2 = (const float*)d_in[13];
    const float* b_gcn2 = (const float*)d_in[14];
    const float* W_dec  = (const float*)d_in[15];
    const float* b_dec  = (const float*)d_in[16];
    const float* W_d1   = (const float*)d_in[17];
    const float* b_d1   = (const float*)d_in[18];
    const float* W_d2   = (const float*)d_in[19];
    const float* b_d2   = (const float*)d_in[20];
    const float* W_d3   = (const float*)d_in[21];
    const float* b_d3   = (const float*)d_in[22];

    const int  N = in_sizes[0] / 128;
    const long E = (long)in_sizes[1] / 2;

    size_t nP = ((size_t)N + 255) & ~(size_t)255;
    size_t eP = ((size_t)E + 255) & ~(size_t)255;
    int*   deg       = (int*)d_ws;
    int*   offs      = deg + nP;             // uses N+1
    int*   cursor    = offs + nP + 256;
    float* dinv      = (float*)(cursor + nP);
    float* a_s       = dinv + nP;
    float* a_d       = a_s + nP;
    int*   flag      = (int*)(a_d + nP);
    int*   blockSums = flag + 256;
    int*   blockOff  = blockSums + 1024;
    int*   csr       = blockOff + 1024;      // E
    unsigned short* h16 = (unsigned short*)(csr + eP);   // N*128 bf16
    unsigned* o16    = (unsigned*)(h16 + nP * 128);      // N*64 u32 (bf16 pairs)
    unsigned* enc16  = o16 + nP * 64;                    // N*64 u32 (bf16 pairs)

    hipMemsetAsync(deg, 0, nP * sizeof(int), stream);
    hipMemsetAsync(cursor, 0, nP * sizeof(int), stream);
    hipMemsetAsync(flag, 0, sizeof(int), stream);

    k_detect<<<16, 256, 0, stream>>>((const int*)edges, 2 * E, flag);

    unsigned eB = (unsigned)((E + 255) / 256);
    k_deg<<<eB, 256, 0, stream>>>(edges, E, flag, deg);

    int nbA = (N + 255) / 256;
    k_scanA<<<nbA, 256, 0, stream>>>(deg, N, offs, blockSums);
    k_scanB<<<1, 1024, 0, stream>>>(blockSums, nbA, blockOff);
    k_scanC<<<nbA, 256, 0, stream>>>(offs, blockOff, deg, dinv, N, E);
    int npp = (N + NSHARD - 1) / NSHARD;
    k_fill<<<eB * NSHARD, 256, 0, stream>>>(edges, E, flag, offs, cursor, csr, npp);

    unsigned aB = (unsigned)((N + 7) / 8);
    unsigned mB = (unsigned)((N + 127) / 128);

    k_denseM<0><<<mB, 512, 0, stream>>>(features, nullptr, mask,
                                        W_gat1, W_gcn1, a_src1, a_dst1, dinv,
                                        h16, a_s, a_d, N);
    k_agg<0><<<aB, 512, 0, stream>>>(offs, csr, a_s, a_d, dinv, h16,
                                     b_gat1, b_gcn1, nullptr, o16, N);
    k_denseM<1><<<mB, 512, 0, stream>>>(nullptr, (const unsigned short*)o16, nullptr,
                                        W_gat2, W_gcn2, a_src2, a_dst2, dinv,
                                        h16, a_s, a_d, N);
    float* out = (float*)d_out;
    float* enc = out + (long)N * 128;
    k_agg<1><<<aB, 512, 0, stream>>>(offs, csr, a_s, a_d, dinv, h16,
                                     b_gat2, b_gcn2, enc, enc16, N);
    k_dense3<<<mB, 512, 0, stream>>>((const unsigned short*)enc16,
                                     W_dec, b_dec, W_d1, b_d1,
                                     W_d2, b_d2, W_d3, b_d3,
                                     out, out + (long)N * 256, N);
}

// Round 20
// 384.926 us; speedup vs baseline: 1.3998x; 1.0100x over previous
//
#include <hip/hip_runtime.h>
#include <math.h>

// ---------------------------------------------------------------------------
// AFPNNet: masked features -> {2-layer GAT, 2-layer GCN} -> concat(encoded)
//          -> recon = relu(enc@Wdec+b), disc = (sigmoid(relu(enc@Wd1+b)@Wd2+b))@Wd3+b
// Outputs flat: recon [N*128] | encoded [N*128] | disc [N]
// h layout: interleaved BF16 [N][128]; csr stores BYTE offsets (src*256).
// LESSON (r4-r7, r14): ANY global weight load in a const-trip k-loop gets
//   serialized/hoisted -> weights MUST be staged in LDS. No exceptions.
// LESSON (r8/r9): k_fill write amplification = cross-XCD dirty-line
//   replication -> dst-shard by blockIdx&7.
// LESSON (r8-r16): VALU dense kernels plateau; MFMA ports broke it. D layout
//   col=lane&15,row=(lane>>4)*4+reg; A/B frag row/col=lane&15,k=(lane>>4)*8+j.
// LESSON (r18/r19): NT stores on final outputs OK; NT load on re-read csr
//   regresses. Wave-uniform broadcasts: readlane, NOT shfl (ds_bpermute).
// r20: k_agg gather pipeline 4->8 deep (VALU 61% / HBM 42% = latency-bound;
//   halve exposed-latency groups per node).
// ---------------------------------------------------------------------------

#define INF_F __int_as_float(0x7f800000)
#define NSHARD 8

typedef __attribute__((ext_vector_type(8))) short bh8;
typedef __attribute__((ext_vector_type(4))) float f32x4;

__device__ __forceinline__ long edge_at(const void* p, int is64, long i) {
    if (is64) return (long)((const long long*)p)[i];
    return (long)((const int*)p)[i];
}

__device__ __forceinline__ unsigned short f2bf(float f) {   // RNE f32->bf16
    unsigned u = __float_as_uint(f);
    return (unsigned short)((u + 0x7FFFu + ((u >> 16) & 1u)) >> 16);
}
__device__ __forceinline__ float bflo(unsigned p) { return __uint_as_float(p << 16); }
__device__ __forceinline__ float bfhi(unsigned p) { return __uint_as_float(p & 0xFFFF0000u); }
__device__ __forceinline__ unsigned pk2bf(float a, float b) {
    return (unsigned)f2bf(a) | ((unsigned)f2bf(b) << 16);
}

__global__ void k_detect(const int* ew, long words, int* flag) {
    long t = (long)blockIdx.x * blockDim.x + threadIdx.x;
    long stride = words / 8192; if (stride < 1) stride = 1;
    long w = 2 * (t * stride) + 1;
    if (t < 4096 && w < words) {
        if (ew[w] != 0) atomicOr(flag, 1);
    }
}

__global__ void k_deg(const void* edges, long E, const int* flag, int* deg) {
    long e = (long)blockIdx.x * blockDim.x + threadIdx.x;
    if (e >= E) return;
    int is64 = (*flag == 0);
    int d = (int)edge_at(edges, is64, E + e);
    atomicAdd(&deg[d], 1);
}

__global__ void k_scanA(const int* deg, int N, int* offs, int* blockSums) {
    __shared__ int s[256];
    int t = threadIdx.x;
    int i = blockIdx.x * 256 + t;
    int v = (i < N) ? deg[i] : 0;
    s[t] = v;
    for (int off = 1; off < 256; off <<= 1) {
        __syncthreads();
        int u = (t >= off) ? s[t - off] : 0;
        __syncthreads();
        s[t] += u;
    }
    __syncthreads();
    if (i < N) offs[i] = s[t] - v;
    if (t == 255) blockSums[blockIdx.x] = s[255];
}

__global__ void k_scanB(const int* blockSums, int nb, int* blockOff) {
    __shared__ int s[1024];
    int t = threadIdx.x;
    int v = (t < nb) ? blockSums[t] : 0;
    s[t] = v;
    for (int off = 1; off < 1024; off <<= 1) {
        __syncthreads();
        int u = (t >= off) ? s[t - off] : 0;
        __syncthreads();
        s[t] += u;
    }
    __syncthreads();
    if (t < nb) blockOff[t] = s[t] - v;
}

__global__ void k_scanC(int* offs, const int* blockOff, const int* deg,
                        float* dinv, int N, long E) {
    int i = blockIdx.x * 256 + threadIdx.x;
    if (i < N) {
        offs[i] += blockOff[i >> 8];
        int dg = deg[i];
        dinv[i] = dg > 0 ? rsqrtf((float)dg) : 0.0f;
    }
    if (i == 0) offs[N] = (int)E;
}

// XCD-sharded CSR fill (see header LESSON r8/r9).
__global__ void k_fill(const void* edges, long E, const int* flag,
                       const int* offs, int* cursor, int* csr_src, int npp) {
    int bid = blockIdx.x;
    int shard = bid & (NSHARD - 1);
    long e = (long)(bid >> 3) * blockDim.x + threadIdx.x;
    if (e >= E) return;
    int is64 = (*flag == 0);
    int d = (int)edge_at(edges, is64, E + e);
    if (d / npp != shard) return;
    int s = (int)edge_at(edges, is64, e);
    int pos = offs[d] + atomicAdd(&cursor[d], 1);
    csr_src[pos] = s << 8;                 // byte offset into [N][128] bf16 rows
}

// Unified MFMA dense layer (mfma_f32_16x16x32_bf16), 128 nodes/block, 8 waves.
template <int MODE>
__global__ __launch_bounds__(512) void k_denseM(
    const float* __restrict__ xf, const unsigned short* __restrict__ a16,
    const int* __restrict__ mask,
    const float* __restrict__ Wa, const float* __restrict__ Wg,
    const float* __restrict__ aSrc, const float* __restrict__ aDst,
    const float* __restrict__ dinv,
    unsigned short* __restrict__ h16,
    float* __restrict__ a_s, float* __restrict__ a_d, int N)
{
    __shared__ unsigned short sB[8 * 4 * 64 * 8];      // 32 KB B-fragments
    __shared__ float sAs[64], sAd[64];
    int t = threadIdx.x;
    for (int slot = t; slot < 2048; slot += 512) {     // nt(8) x ks(4) x lane(64)
        int l = slot & 63, ntks = slot >> 6, ks = ntks & 3, nt = ntks >> 2;
        int col = nt * 16 + (l & 15);
        int kbase = ks * 32 + ((l >> 4) << 3);
#pragma unroll
        for (int j = 0; j < 8; ++j) {
            int k = kbase + j;
            float v;
            if (MODE == 0) {
                v = (col < 64) ? Wa[k * 64 + col] : Wg[k * 64 + (col - 64)];
            } else {
                if (col < 64) v = (k < 64) ? Wa[k * 64 + col] : 0.f;
                else          v = (k >= 64) ? Wg[(k - 64) * 64 + (col - 64)] : 0.f;
            }
            sB[slot * 8 + j] = f2bf(v);
        }
    }
    if (t < 64) { sAs[t] = aSrc[t]; sAd[t] = aDst[t]; }
    __syncthreads();

    int w = t >> 6, lane = t & 63;
    int base = blockIdx.x * 128 + w * 16;
    int arow = base + (lane & 15);
    int acl = arow < N ? arow : 0;

    bh8 afr[4];
    if (MODE == 0) {
        float msk = (arow < N && mask[acl] != 1) ? 1.f : 0.f;
        const float* ap = xf + (long)acl * 128 + ((lane >> 4) << 3);
#pragma unroll
        for (int ks = 0; ks < 4; ++ks) {
            float4 u0 = *(const float4*)(ap + ks * 32);
            float4 u1 = *(const float4*)(ap + ks * 32 + 4);
            union { bh8 v; unsigned u4[4]; } cv;
            cv.u4[0] = pk2bf(u0.x * msk, u0.y * msk);
            cv.u4[1] = pk2bf(u0.z * msk, u0.w * msk);
            cv.u4[2] = pk2bf(u1.x * msk, u1.y * msk);
            cv.u4[3] = pk2bf(u1.z * msk, u1.w * msk);
            afr[ks] = cv.v;
        }
    } else {
        const unsigned short* ap = a16 + (long)acl * 128 + ((lane >> 4) << 3);
#pragma unroll
        for (int ks = 0; ks < 4; ++ks) afr[ks] = *(const bh8*)(ap + ks * 32);
    }

    f32x4 acc[8];
#pragma unroll
    for (int i = 0; i < 8; ++i) acc[i] = (f32x4){0.f, 0.f, 0.f, 0.f};
#pragma unroll
    for (int ks = 0; ks < 4; ++ks) {
#pragma unroll
        for (int nt = 0; nt < 8; ++nt) {
            bh8 b = *(const bh8*)&sB[((nt * 4 + ks) * 64 + lane) * 8];
            acc[nt] = __builtin_amdgcn_mfma_f32_16x16x32_bf16(afr[ks], b, acc[nt], 0, 0, 0);
        }
    }

    int rb = base + ((lane >> 4) << 2);
    float dvr[4];
#pragma unroll
    for (int r = 0; r < 4; ++r) dvr[r] = (rb + r < N) ? dinv[rb + r] : 0.f;

    float pa[4] = {0.f, 0.f, 0.f, 0.f}, pd[4] = {0.f, 0.f, 0.f, 0.f};
#pragma unroll
    for (int nt = 0; nt < 4; ++nt) {
        float as = sAs[nt * 16 + (lane & 15)];
        float ad = sAd[nt * 16 + (lane & 15)];
#pragma unroll
        for (int r = 0; r < 4; ++r) {
            pa[r] = fmaf(acc[nt][r], as, pa[r]);
            pd[r] = fmaf(acc[nt][r], ad, pd[r]);
        }
    }
#pragma unroll
    for (int r = 0; r < 4; ++r) {
#pragma unroll
        for (int off = 8; off; off >>= 1) {
            pa[r] += __shfl_xor(pa[r], off);
            pd[r] += __shfl_xor(pd[r], off);
        }
        int grow = rb + r;
        if ((lane & 15) == 0 && grow < N) { a_s[grow] = pa[r]; a_d[grow] = pd[r]; }
    }
#pragma unroll
    for (int nt = 0; nt < 8; ++nt) {
        int col = nt * 16 + (lane & 15);
        bool gcn = nt >= 4;
#pragma unroll
        for (int r = 0; r < 4; ++r) {
            int grow = rb + r;
            if (grow < N) {
                float v = acc[nt][r];
                if (gcn) v *= dvr[r];
                h16[(long)grow * 128 + col] = f2bf(v);
            }
        }
    }
}

// Fused aggregation, wave per dst node. h rows bf16; 8-deep gather pipeline.
// MODE 0: writes o16 only. MODE 1: f32 enc (NT) + enc16.
template <int MODE>
__global__ __launch_bounds__(512) void k_agg(
    const int* __restrict__ offs, const int* __restrict__ csr,
    const float* __restrict__ a_s, const float* __restrict__ a_d,
    const float* __restrict__ dinv,
    const unsigned short* __restrict__ h16,
    const float* __restrict__ b_a, const float* __restrict__ b_g,
    float* __restrict__ out, unsigned* __restrict__ o16, int N)
{
    int node = blockIdx.x * 8 + (threadIdx.x >> 6);
    int lane = threadIdx.x & 63;
    if (node >= N) return;
    int p0 = offs[node], p1 = offs[node + 1];
    int deg = p1 - p0;
    float adst = a_d[node];
    float dv = dinv[node];
    bool gat = lane < 32;
    const char* hb = (const char*)h16 + lane * 4;

    float2 res = make_float2(0.f, 0.f);
    if (deg > 0 && deg <= 64) {
        int soff = (lane < deg) ? csr[p0 + lane] : 0;
        float att = -INF_F;
        if (lane < deg) {
            float a = a_s[soff >> 8] + adst;
            att = a >= 0.f ? a : 0.2f * a;
        }
        float m = att;
#pragma unroll
        for (int off = 32; off; off >>= 1) m = fmaxf(m, __shfl_xor(m, off));
        float w = (lane < deg) ? __expf(att - m) : 0.f;
        float den = w;
#pragma unroll
        for (int off = 32; off; off >>= 1) den += __shfl_xor(den, off);
        float coefl = w / den;
        int coefi = __float_as_int(coefl);

        float2 ac[8];
#pragma unroll
        for (int i = 0; i < 8; ++i) ac[i] = make_float2(0.f, 0.f);
        int e = 0;
        for (; e + 8 <= deg; e += 8) {
            int og[8]; unsigned vg[8]; float cg[8];
#pragma unroll
            for (int i = 0; i < 8; ++i) og[i] = __builtin_amdgcn_readlane(soff, e + i);
#pragma unroll
            for (int i = 0; i < 8; ++i) vg[i] = *(const unsigned*)(hb + og[i]);
#pragma unroll
            for (int i = 0; i < 8; ++i)
                cg[i] = __int_as_float(__builtin_amdgcn_readlane(coefi, e + i));
#pragma unroll
            for (int i = 0; i < 8; ++i) {
                float wi = gat ? cg[i] : 1.f;
                ac[i].x = fmaf(bflo(vg[i]), wi, ac[i].x);
                ac[i].y = fmaf(bfhi(vg[i]), wi, ac[i].y);
            }
        }
        if (e + 4 <= deg) {
            int og[4]; unsigned vg[4]; float cg[4];
#pragma unroll
            for (int i = 0; i < 4; ++i) og[i] = __builtin_amdgcn_readlane(soff, e + i);
#pragma unroll
            for (int i = 0; i < 4; ++i) vg[i] = *(const unsigned*)(hb + og[i]);
#pragma unroll
            for (int i = 0; i < 4; ++i)
                cg[i] = __int_as_float(__builtin_amdgcn_readlane(coefi, e + i));
#pragma unroll
            for (int i = 0; i < 4; ++i) {
                float wi = gat ? cg[i] : 1.f;
                ac[i].x = fmaf(bflo(vg[i]), wi, ac[i].x);
                ac[i].y = fmaf(bfhi(vg[i]), wi, ac[i].y);
            }
            e += 4;
        }
        for (; e < deg; ++e) {
            int oe = __builtin_amdgcn_readlane(soff, e);
            float ce = __int_as_float(__builtin_amdgcn_readlane(coefi, e));
            unsigned v = *(const unsigned*)(hb + oe);
            float we = gat ? ce : 1.f;
            ac[0].x = fmaf(bflo(v), we, ac[0].x);
            ac[0].y = fmaf(bfhi(v), we, ac[0].y);
        }
        res.x = ((ac[0].x + ac[1].x) + (ac[2].x + ac[3].x))
              + ((ac[4].x + ac[5].x) + (ac[6].x + ac[7].x));
        res.y = ((ac[0].y + ac[1].y) + (ac[2].y + ac[3].y))
              + ((ac[4].y + ac[5].y) + (ac[6].y + ac[7].y));
    } else if (deg > 64) {
        float m = -INF_F, den = 0.f;
        float2 aa = make_float2(0.f, 0.f);
        for (int p = p0; p < p1; ++p) {
            int soff = csr[p];
            float a = a_s[soff >> 8] + adst;
            float att = a >= 0.f ? a : 0.2f * a;
            float mn = fmaxf(m, att);
            float r = __expf(m - mn);
            float w = __expf(att - mn);
            den = den * r + w;
            unsigned v = *(const unsigned*)(hb + soff);
            float reff = gat ? r : 1.f, weff = gat ? w : 1.f;
            aa.x = fmaf(aa.x, reff, weff * bflo(v));
            aa.y = fmaf(aa.y, reff, weff * bfhi(v));
            m = mn;
        }
        if (gat) { res.x = aa.x / den; res.y = aa.y / den; }
        else     { res = aa; }
    }

    int col = lane * 2;
    float2 ov;
    if (gat) {
        ov.x = res.x + b_a[col];
        ov.y = res.y + b_a[col + 1];
        if (MODE == 0) {
            ov.x = ov.x > 0.f ? ov.x : (__expf(ov.x) - 1.f);
            ov.y = ov.y > 0.f ? ov.y : (__expf(ov.y) - 1.f);
        }
    } else {
        ov.x = dv * res.x + b_g[col - 64];
        ov.y = dv * res.y + b_g[col - 63];
        if (MODE == 0) {
            ov.x = fmaxf(ov.x, 0.f);
            ov.y = fmaxf(ov.y, 0.f);
        }
    }
    if (MODE == 1) {
        __builtin_nontemporal_store(ov.x, &out[(long)node * 128 + col]);
        __builtin_nontemporal_store(ov.y, &out[(long)node * 128 + col + 1]);
    }
    o16[(long)node * 64 + lane] = pk2bf(ov.x, ov.y);
}

// Fused decoder + discriminator on MATRIX cores (r16; recon/disc stores NT).
__global__ __launch_bounds__(512) void k_dense3(
    const unsigned short* __restrict__ enc16,
    const float* __restrict__ Wdec, const float* __restrict__ bdec,
    const float* __restrict__ Wd1, const float* __restrict__ bd1,
    const float* __restrict__ Wd2, const float* __restrict__ bd2,
    const float* __restrict__ Wd3, const float* __restrict__ bd3,
    float* __restrict__ recon, float* __restrict__ disc, int N)
{
    __shared__ unsigned short sBdec[8 * 4 * 64 * 8];   // 32 KB
    __shared__ unsigned short sBd1[4 * 4 * 64 * 8];    // 16 KB
    __shared__ unsigned short sBd2[2 * 2 * 64 * 8];    // 4 KB
    __shared__ unsigned short sd1[128 * 64];           // 16 KB (row-major bf16)
    __shared__ float sWd3[32];
    int t = threadIdx.x;
    for (int slot = t; slot < 2048; slot += 512) {     // Wdec: 8nt*4ks*64l
        int l = slot & 63, ntks = slot >> 6, ks = ntks & 3, nt = ntks >> 2;
        int krow = ks * 32 + ((l >> 4) << 3);
        int col = nt * 16 + (l & 15);
#pragma unroll
        for (int j = 0; j < 8; ++j)
            sBdec[slot * 8 + j] = f2bf(Wdec[(krow + j) * 128 + col]);
    }
    for (int slot = t; slot < 1024; slot += 512) {     // Wd1: 4nt*4ks*64l
        int l = slot & 63, ntks = slot >> 6, ks = ntks & 3, nt = ntks >> 2;
        int krow = ks * 32 + ((l >> 4) << 3);
        int col = nt * 16 + (l & 15);
#pragma unroll
        for (int j = 0; j < 8; ++j)
            sBd1[slot * 8 + j] = f2bf(Wd1[(krow + j) * 64 + col]);
    }
    if (t < 256) {                                     // Wd2: 2nt*2ks*64l
        int slot = t;
        int l = slot & 63, ntks = slot >> 6, ks = ntks & 1, nt = ntks >> 1;
        int krow = ks * 32 + ((l >> 4) << 3);
        int col = nt * 16 + (l & 15);
#pragma unroll
        for (int j = 0; j < 8; ++j)
            sBd2[slot * 8 + j] = f2bf(Wd2[(krow + j) * 32 + col]);
    }
    if (t < 32) sWd3[t] = Wd3[t];
    __syncthreads();

    int w = t >> 6, lane = t & 63;
    int base = blockIdx.x * 128 + w * 16;
    int arow = base + (lane & 15);
    int acl = arow < N ? arow : 0;
    const unsigned short* ap = enc16 + (long)acl * 128 + ((lane >> 4) << 3);

    f32x4 accR[8], accD1[4];
#pragma unroll
    for (int i = 0; i < 8; ++i) accR[i] = (f32x4){0.f, 0.f, 0.f, 0.f};
#pragma unroll
    for (int i = 0; i < 4; ++i) accD1[i] = (f32x4){0.f, 0.f, 0.f, 0.f};
#pragma unroll
    for (int ks = 0; ks < 4; ++ks) {
        bh8 a = *(const bh8*)(ap + ks * 32);
#pragma unroll
        for (int nt = 0; nt < 8; ++nt) {
            bh8 b = *(const bh8*)&sBdec[((nt * 4 + ks) * 64 + lane) * 8];
            accR[nt] = __builtin_amdgcn_mfma_f32_16x16x32_bf16(a, b, accR[nt], 0, 0, 0);
        }
#pragma unroll
        for (int nt = 0; nt < 4; ++nt) {
            bh8 b = *(const bh8*)&sBd1[((nt * 4 + ks) * 64 + lane) * 8];
            accD1[nt] = __builtin_amdgcn_mfma_f32_16x16x32_bf16(a, b, accD1[nt], 0, 0, 0);
        }
    }
    int rb = base + ((lane >> 4) << 2);
#pragma unroll
    for (int nt = 0; nt < 8; ++nt) {
        int col = nt * 16 + (lane & 15);
        float bcol = bdec[col];
#pragma unroll
        for (int r = 0; r < 4; ++r) {
            int grow = rb + r;
            if (grow < N)
                __builtin_nontemporal_store(fmaxf(accR[nt][r] + bcol, 0.f),
                                            &recon[(long)grow * 128 + col]);
        }
    }
    int lrb = w * 16 + ((lane >> 4) << 2);
#pragma unroll
    for (int nt = 0; nt < 4; ++nt) {
        int col = nt * 16 + (lane & 15);
        float bcol = bd1[col];
#pragma unroll
        for (int r = 0; r < 4; ++r)
            sd1[(lrb + r) * 64 + col] = f2bf(fmaxf(accD1[nt][r] + bcol, 0.f));
    }
    __syncthreads();
    f32x4 accD2[2];
    accD2[0] = (f32x4){0.f, 0.f, 0.f, 0.f};
    accD2[1] = (f32x4){0.f, 0.f, 0.f, 0.f};
#pragma unroll
    for (int ks = 0; ks < 2; ++ks) {
        bh8 a = *(const bh8*)&sd1[(w * 16 + (lane & 15)) * 64 + ks * 32 + ((lane >> 4) << 3)];
#pragma unroll
        for (int nt = 0; nt < 2; ++nt) {
            bh8 b = *(const bh8*)&sBd2[((nt * 2 + ks) * 64 + lane) * 8];
            accD2[nt] = __builtin_amdgcn_mfma_f32_16x16x32_bf16(a, b, accD2[nt], 0, 0, 0);
        }
    }
    float b2a = bd2[lane & 15], b2b = bd2[16 + (lane & 15)];
    float w3a = sWd3[lane & 15], w3b = sWd3[16 + (lane & 15)];
    float b3 = bd3[0];
#pragma unroll
    for (int r = 0; r < 4; ++r) {
        float v = w3a / (1.f + __expf(-(accD2[0][r] + b2a)))
                + w3b / (1.f + __expf(-(accD2[1][r] + b2b)));
        v += __shfl_xor(v, 1); v += __shfl_xor(v, 2);
        v += __shfl_xor(v, 4); v += __shfl_xor(v, 8);
        int grow = rb + r;
        if ((lane & 15) == 0 && grow < N)
            __builtin_nontemporal_store(v + b3, &disc[grow]);
    }
}

extern "C" void kernel_launch(void* const* d_in, const int* in_sizes, int n_in,
                              void* d_out, int out_size, void* d_ws, size_t ws_size,
                              hipStream_t stream)
{
    const float* features = (const float*)d_in[0];
    const void*  edges    = d_in[1];
    const int*   mask     = (const int*)d_in[2];
    const float* W_gat1 = (const float*)d_in[3];
    const float* a_src1 = (const float*)d_in[4];
    const float* a_dst1 = (const float*)d_in[5];
    const float* b_gat1 = (const float*)d_in[6];
    const float* W_gat2 = (const float*)d_in[7];
    const float* a_src2 = (const float*)d_in[8];
    const float* a_dst2 = (const float*)d_in[9];
    const float* b_gat2 = (const float*)d_in[10];
    const float* W_gcn1 = (const float*)d_in[11];
    const float* b_gcn1 = (const float*)d_in[12];
    const float* W_gcn2 = (const float*)d_in[13];
    const float* b_gcn2 = (const float*)d_in[14];
    const float* W_dec  = (const float*)d_in[15];
    const float* b_dec  = (const float*)d_in[16];
    const float* W_d1   = (const float*)d_in[17];
    const float* b_d1   = (const float*)d_in[18];
    const float* W_d2   = (const float*)d_in[19];
    const float* b_d2   = (const float*)d_in[20];
    const float* W_d3   = (const float*)d_in[21];
    const float* b_d3   = (const float*)d_in[22];

    const int  N = in_sizes[0] / 128;
    const long E = (long)in_sizes[1] / 2;

    size_t nP = ((size_t)N + 255) & ~(size_t)255;
    size_t eP = ((size_t)E + 255) & ~(size_t)255;
    int*   deg       = (int*)d_ws;
    int*   offs      = deg + nP;             // uses N+1
    int*   cursor    = offs + nP + 256;
    float* dinv      = (float*)(cursor + nP);
    float* a_s       = dinv + nP;
    float* a_d       = a_s + nP;
    int*   flag      = (int*)(a_d + nP);
    int*   blockSums = flag + 256;
    int*   blockOff  = blockSums + 1024;
    int*   csr       = blockOff + 1024;      // E
    unsigned short* h16 = (unsigned short*)(csr + eP);   // N*128 bf16
    unsigned* o16    = (unsigned*)(h16 + nP * 128);      // N*64 u32 (bf16 pairs)
    unsigned* enc16  = o16 + nP * 64;                    // N*64 u32 (bf16 pairs)

    hipMemsetAsync(deg, 0, nP * sizeof(int), stream);
    hipMemsetAsync(cursor, 0, nP * sizeof(int), stream);
    hipMemsetAsync(flag, 0, sizeof(int), stream);

    k_detect<<<16, 256, 0, stream>>>((const int*)edges, 2 * E, flag);

    unsigned eB = (unsigned)((E + 255) / 256);
    k_deg<<<eB, 256, 0, stream>>>(edges, E, flag, deg);

    int nbA = (N + 255) / 256;
    k_scanA<<<nbA, 256, 0, stream>>>(deg, N, offs, blockSums);
    k_scanB<<<1, 1024, 0, stream>>>(blockSums, nbA, blockOff);
    k_scanC<<<nbA, 256, 0, stream>>>(offs, blockOff, deg, dinv, N, E);
    int npp = (N + NSHARD - 1) / NSHARD;
    k_fill<<<eB * NSHARD, 256, 0, stream>>>(edges, E, flag, offs, cursor, csr, npp);

    unsigned aB = (unsigned)((N + 7) / 8);
    unsigned mB = (unsigned)((N + 127) / 128);

    k_denseM<0><<<mB, 512, 0, stream>>>(features, nullptr, mask,
                                        W_gat1, W_gcn1, a_src1, a_dst1, dinv,
                                        h16, a_s, a_d, N);
    k_agg<0><<<aB, 512, 0, stream>>>(offs, csr, a_s, a_d, dinv, h16,
                                     b_gat1, b_gcn1, nullptr, o16, N);
    k_denseM<1><<<mB, 512, 0, stream>>>(nullptr, (const unsigned short*)o16, nullptr,
                                        W_gat2, W_gcn2, a_src2, a_dst2, dinv,
                                        h16, a_s, a_d, N);
    float* out = (float*)d_out;
    float* enc = out + (long)N * 128;
    k_agg<1><<<aB, 512, 0, stream>>>(offs, csr, a_s, a_d, dinv, h16,
                                     b_gat2, b_gcn2, enc, enc16, N);
    k_dense3<<<mB, 512, 0, stream>>>((const unsigned short*)enc16,
                                     W_dec, b_dec, W_d1, b_d1,
                                     W_d2, b_d2, W_d3, b_d3,
                                     out, out + (long)N * 256, N);
}